// Round 13
// baseline (272.234 us; speedup 1.0000x reference)
//
#include <hip/hip_runtime.h>

#define NROI  2048
#define CCH   256
#define IMH   200
#define IMW   200
#define CROP  7
#define PP    49
#define FANIN 12544
#define HID   1024
#define OCTR  25                  // rows per octant
#define SLR   26                  // staged rows (incl guard)

typedef _Float16 f16x8 __attribute__((ext_vector_type(8)));
typedef _Float16 f16x4 __attribute__((ext_vector_type(4)));
typedef __attribute__((ext_vector_type(4))) float f32x4;

__device__ __forceinline__ void gload16(const void* g, void* l) {
    __builtin_amdgcn_global_load_lds(
        (const __attribute__((address_space(1))) void*)g,
        (__attribute__((address_space(3))) void*)l, 16, 0, 0);
}

// ---------------------------------------------------------------------------
// zero the 32 per-(image,octant) counters (ws not re-poisoned between replays)
// ---------------------------------------------------------------------------
__global__ void zero_cnt_kernel(int* __restrict__ cnt) {
    if (threadIdx.x < 32) cnt[threadIdx.x] = 0;
}

// ---------------------------------------------------------------------------
// Geometry binned by y-octant. One thread per ROI. For each bin-row i
// (7 bins share y0 -> same octant q=y0/25), atomically append 7 packed
// samples to the dense list of (image b, octant q):
//   { x0 | y0rel<<8 | dx<<16 | dy<<17, wx, wy, n*FANIN + i*7 + j }.
// List order is nondeterministic; final crops content is not (each sample
// owns its output slot).
// ---------------------------------------------------------------------------
__global__ __launch_bounds__(256) void roi_geom_kernel(
    const float* __restrict__ rois, uint4* __restrict__ geomD,
    int* __restrict__ cnt)
{
    const int n = blockIdx.x * 256 + threadIdx.x;
    if (n >= NROI) return;

    const int b = (int)rois[(size_t)n * 5 + 0];
    const float rx1 = rois[(size_t)n * 5 + 1];
    const float ry1 = rois[(size_t)n * 5 + 2];
    const float rx2 = rois[(size_t)n * 5 + 3];
    const float ry2 = rois[(size_t)n * 5 + 4];
    const float bw = (rx2 - rx1) / 7.0f;
    const float bh = (ry2 - ry1) / 7.0f;

    unsigned xbits[7]; unsigned xw[7];
#pragma unroll
    for (int j = 0; j < 7; ++j) {
        float px = __fadd_rn(rx1, __fmul_rn((float)j + 0.5f, bw));
        px = fminf(fmaxf(px, 0.0f), (float)(IMW - 1));
        const float fx = floorf(px);
        const int x0 = (int)fx;
        const int dx = min(x0 + 1, IMW - 1) - x0;
        xbits[j] = (unsigned)x0 | ((unsigned)dx << 16);
        xw[j] = __float_as_uint(px - fx);
    }

#pragma unroll
    for (int i = 0; i < 7; ++i) {
        float py = __fadd_rn(ry1, __fmul_rn((float)i + 0.5f, bh));
        py = fminf(fmaxf(py, 0.0f), (float)(IMH - 1));
        const float fy = floorf(py);
        const int y0 = (int)fy;
        const int dy = min(y0 + 1, IMH - 1) - y0;
        const unsigned wy = __float_as_uint(py - fy);
        const int q = y0 / OCTR;                    // 0..7
        const int y0r = y0 - q * OCTR;              // 0..24
        const unsigned ybits = ((unsigned)y0r << 8) | ((unsigned)dy << 17);

        const int base = atomicAdd(&cnt[b * 8 + q], 7);
        uint4* dst = geomD + (size_t)(b * 8 + q) * (NROI * PP) + base;
#pragma unroll
        for (int j = 0; j < 7; ++j)
            dst[j] = make_uint4(xbits[j] | ybits, xw[j], wy,
                                (unsigned)(n * FANIN + i * 7 + j));
    }
}

// ---------------------------------------------------------------------------
// RoIAlign: block = (channel c, image b, octant q). Stage 26 rows (20.8 KB
// f32) via async global_load_lds (7 blocks/CU -> stages overlap sweeps of
// co-resident blocks). Sweep the (b,q) dense sample list: 1 sample/lane,
// depth-2 prefetch, f32 exact bilinear, f16 output.
// ---------------------------------------------------------------------------
__global__ __launch_bounds__(256) void roi_align_kernel(
    const float* __restrict__ x, const uint4* __restrict__ geomD,
    const int* __restrict__ cnt, _Float16* __restrict__ crops)
{
    __shared__ float slab[SLR * IMW];              // 20,800 B

    const int c = blockIdx.x;
    const int b = blockIdx.y;
    const int q = blockIdx.z;
    const int tid = threadIdx.x;

    // ---- stage: nrows*800 B async DMA ----
    const int nrows = (q < 7) ? SLR : OCTR;        // guard row except last oct
    const char* src = (const char*)(x + ((size_t)(b * CCH + c)) * (IMH * IMW)
                                      + (size_t)q * OCTR * IMW);
    char* sl = (char*)slab;
    const int t16 = nrows * 50;                    // 16B chunks
    for (int t = tid; t < t16; t += 256)
        gload16(src + t * 16, sl + t * 16);
    __syncthreads();                               // vmcnt(0) drain

    const int S = cnt[b * 8 + q];
    const uint4* gD = geomD + (size_t)(b * 8 + q) * (NROI * PP);
    const int cOff = c * PP;

    int s = tid;
    uint4 g = make_uint4(0, 0, 0, 0);
    if (S > 0) g = gD[min(s, S - 1)];

    while (s < S) {
        const int sn = s + 256;
        uint4 gn = g;
        if (sn < S) gn = gD[sn];

        const unsigned w0 = g.x;
        const int a00 = (int)((w0 >> 8) & 255) * IMW + (int)(w0 & 255);
        const int dx  = (w0 >> 16) & 1;
        const int a10 = a00 + ((w0 >> 17) & 1) * IMW;
        const float v00 = slab[a00];
        const float v01 = slab[a00 + dx];
        const float v10 = slab[a10];
        const float v11 = slab[a10 + dx];
        const float wx = __uint_as_float(g.y);
        const float wy = __uint_as_float(g.z);
        const float top = v00 + wx * (v01 - v00);
        const float bot = v10 + wx * (v11 - v10);
        const float val = top + wy * (bot - top);
        crops[g.w + cOff] = (_Float16)val;

        s = sn; g = gn;
    }
}

// ---------------------------------------------------------------------------
// f32 -> f16 weight conversion, vectorized (4 elems/thread).
// ---------------------------------------------------------------------------
__global__ __launch_bounds__(256) void convert_f16(
    const float* __restrict__ w, _Float16* __restrict__ wF, int n4)
{
    for (int g = blockIdx.x * 256 + threadIdx.x; g < n4; g += gridDim.x * 256) {
        const float4 v = ((const float4*)w)[g];
        f16x4 o = {(_Float16)v.x, (_Float16)v.y, (_Float16)v.z, (_Float16)v.w};
        ((f16x4*)wF)[g] = o;
    }
}

// ---------------------------------------------------------------------------
// f16 MFMA GEMM (NT), BK=64: P[z] = A[M,K] * B[N,K]^T over K-slice z.
// 128x128 tile, 4 waves of 64x64; 32 MFMA per barrier-pair.
// ---------------------------------------------------------------------------
__global__ __launch_bounds__(256, 3) void gemm_f16(
    const _Float16* __restrict__ A, const _Float16* __restrict__ B,
    float* __restrict__ P, int M, int N, int K, int kLen)
{
    __shared__ _Float16 lds[2][128][64];   // A, B tiles (16 KB each)

    const int tid  = threadIdx.x;
    const int wave = tid >> 6;
    const int lane = tid & 63;
    const int bm = blockIdx.y * 128;
    const int bn = blockIdx.x * 128;
    const int kBase = blockIdx.z * kLen;
    const int wr = wave >> 1, wc = wave & 1;

    f32x4 acc[4][4];
#pragma unroll
    for (int i = 0; i < 4; ++i)
#pragma unroll
        for (int j = 0; j < 4; ++j) acc[i][j] = (f32x4){0.f, 0.f, 0.f, 0.f};

    const int r_st = wave * 32 + (lane >> 3);
    const int s_st = ((lane & 7) ^ ((lane >> 4) & 3)) * 8;   // f16 units
    const _Float16* gA = A + (size_t)(bm + r_st) * K + kBase + s_st;
    const _Float16* gB = B + (size_t)(bn + r_st) * K + kBase + s_st;
    const size_t rstep8 = (size_t)8 * K;
    _Float16* lA = &lds[0][wave * 32][0];
    _Float16* lB = &lds[1][wave * 32][0];

    const int li = lane & 15;
    const int hi = lane >> 4;            // 0..3
    const int swb = (li >> 1) & 3;       // row-pair xor term

    for (int kt = 0; kt < kLen; kt += 64) {
#pragma unroll
        for (int ck = 0; ck < 4; ++ck) {
            gload16(gA + kt + ck * rstep8, lA + ck * 512);
            gload16(gB + kt + ck * rstep8, lB + ck * 512);
        }
        __syncthreads();

#pragma unroll
        for (int kk = 0; kk < 2; ++kk) {
            const int sw = (((kk << 2) | hi) ^ swb) * 8;     // f16 offset
            f16x8 a[4], b[4];
#pragma unroll
            for (int m = 0; m < 4; ++m)
                a[m] = *(const f16x8*)&lds[0][wr * 64 + m * 16 + li][sw];
#pragma unroll
            for (int n = 0; n < 4; ++n)
                b[n] = *(const f16x8*)&lds[1][wc * 64 + n * 16 + li][sw];
#pragma unroll
            for (int m = 0; m < 4; ++m)
#pragma unroll
                for (int n = 0; n < 4; ++n)
                    acc[m][n] = __builtin_amdgcn_mfma_f32_16x16x32_f16(a[m], b[n], acc[m][n], 0, 0, 0);
        }
        __syncthreads();
    }

    float* Pz = P + (size_t)blockIdx.z * M * N;
#pragma unroll
    for (int m = 0; m < 4; ++m)
#pragma unroll
        for (int n = 0; n < 4; ++n) {
            const int col = bn + wc * 64 + n * 16 + li;
#pragma unroll
            for (int e = 0; e < 4; ++e) {
                const int row = bm + wr * 64 + m * 16 + hi * 4 + e;
                Pz[(size_t)row * N + col] = acc[m][n][e];
            }
        }
}

// ---------------------------------------------------------------------------
// relu(sum_z P[z] + bias) -> f16
// ---------------------------------------------------------------------------
__global__ __launch_bounds__(256) void combine_relu_f16(
    const float* __restrict__ P, int Z, const float* __restrict__ bias,
    _Float16* __restrict__ H)
{
    const int g = blockIdx.x * 256 + threadIdx.x;
    const size_t MN4 = (size_t)NROI * HID / 4;
    float4 s = ((const float4*)P)[g];
    for (int z = 1; z < Z; ++z) {
        const float4 p = ((const float4*)P)[z * MN4 + g];
        s.x += p.x; s.y += p.y; s.z += p.z; s.w += p.w;
    }
    const float4 bv = *(const float4*)(bias + (g & 255) * 4);
    f16x4 o = {(_Float16)fmaxf(s.x + bv.x, 0.0f),
               (_Float16)fmaxf(s.y + bv.y, 0.0f),
               (_Float16)fmaxf(s.z + bv.z, 0.0f),
               (_Float16)fmaxf(s.w + bv.w, 0.0f)};
    ((f16x4*)H)[g] = o;
}

// ---------------------------------------------------------------------------
// relu(sum_z P[z] + bias) -> f32 (aliases P[0] elementwise - safe)
// ---------------------------------------------------------------------------
__global__ __launch_bounds__(256) void combine_relu_f32(
    const float* __restrict__ P, int Z, const float* __restrict__ bias,
    float* __restrict__ H)
{
    const int g = blockIdx.x * 256 + threadIdx.x;
    const size_t MN4 = (size_t)NROI * HID / 4;
    float4 s = ((const float4*)P)[g];
    for (int z = 1; z < Z; ++z) {
        const float4 p = ((const float4*)P)[z * MN4 + g];
        s.x += p.x; s.y += p.y; s.z += p.z; s.w += p.w;
    }
    const float4 bv = *(const float4*)(bias + (g & 255) * 4);
    float4 r;
    r.x = fmaxf(s.x + bv.x, 0.0f);
    r.y = fmaxf(s.y + bv.y, 0.0f);
    r.z = fmaxf(s.z + bv.z, 0.0f);
    r.w = fmaxf(s.w + bv.w, 0.0f);
    ((float4*)H)[g] = r;
}

// ---------------------------------------------------------------------------
// heads: one wave per ROI row; 10 dots of K=1024, shfl_xor reduce.
// ---------------------------------------------------------------------------
__global__ __launch_bounds__(256) void heads_kernel(
    const float* __restrict__ h2,
    const float* __restrict__ wc, const float* __restrict__ bc,
    const float* __restrict__ wb, const float* __restrict__ bb,
    float* __restrict__ out)
{
    const int gw   = (blockIdx.x * 256 + threadIdx.x) >> 6;
    const int lane = threadIdx.x & 63;
    const float* hrow = h2 + (size_t)gw * HID;

    float4 h[4];
#pragma unroll
    for (int j = 0; j < 4; ++j)
        h[j] = *(const float4*)(hrow + lane * 16 + j * 4);

    float keep = 0.0f;
#pragma unroll
    for (int o = 0; o < 10; ++o) {
        const float* wrow = (o < 2) ? (wc + (size_t)o * HID)
                                    : (wb + (size_t)(o - 2) * HID);
        float acc = 0.0f;
#pragma unroll
        for (int j = 0; j < 4; ++j) {
            const float4 w4 = *(const float4*)(wrow + lane * 16 + j * 4);
            acc += h[j].x * w4.x + h[j].y * w4.y + h[j].z * w4.z + h[j].w * w4.w;
        }
#pragma unroll
        for (int s = 32; s; s >>= 1) acc += __shfl_xor(acc, s, 64);
        if (lane == o) keep = acc;
    }
    if (lane < 2)        out[gw * 2 + lane] = keep + bc[lane];
    else if (lane < 10)  out[NROI * 2 + gw * 8 + (lane - 2)] = keep + bb[lane - 2];
}

// ---------------------------------------------------------------------------
extern "C" void kernel_launch(void* const* d_in, const int* in_sizes, int n_in,
                              void* d_out, int out_size, void* d_ws, size_t ws_size,
                              hipStream_t stream)
{
    const float* x    = (const float*)d_in[0];
    const float* rois = (const float*)d_in[1];
    const float* w1   = (const float*)d_in[2];
    const float* b1   = (const float*)d_in[3];
    const float* w2   = (const float*)d_in[4];
    const float* b2   = (const float*)d_in[5];
    const float* wc   = (const float*)d_in[6];
    const float* bc   = (const float*)d_in[7];
    const float* wb   = (const float*)d_in[8];
    const float* bb   = (const float*)d_in[9];
    float* out = (float*)d_out;

    char* ws = (char*)d_ws;
    const size_t CRB = (size_t)NROI * FANIN * 2;       // 51,380,224
    const size_t W1B = (size_t)HID * FANIN * 2;        // 25,690,112
    const size_t W2B = (size_t)HID * HID * 2;          //  2,097,152
    const size_t PB  = (size_t)NROI * HID * 4;         //  8,388,608 per z-slice
    const size_t HB  = (size_t)NROI * HID * 2;         //  4,194,304
    const size_t GDB = (size_t)32 * NROI * PP * 16;    // 51,380,224

    const int Z1 = 7;   // FC1 K-split: 12544/7 = 1792 = 28 x 64
    const int Z2 = 4;   // FC2 K-split: 1024/4  = 256 =  4 x 64

    size_t off = 0;
    _Float16* cropsF = (_Float16*)(ws + off); off += CRB;
    _Float16* w1F    = (_Float16*)(ws + off); off += W1B;
    _Float16* w2F    = (_Float16*)(ws + off); off += W2B;
    float*    P      = (float*)(ws + off);    off += (size_t)Z1 * PB;
    _Float16* h1F    = (_Float16*)(ws + off); off += HB;
    uint4*    geomD  = (uint4*)(ws + off);    off += GDB;
    int*      cnt    = (int*)(ws + off);      off += 128;
    float*    h2     = P;   // elementwise alias with P[0] in combine_relu_f32

    // geometry binned by (image, y-octant)
    zero_cnt_kernel<<<1, 64, 0, stream>>>(cnt);
    roi_geom_kernel<<<NROI / 256, 256, 0, stream>>>(rois, geomD, cnt);

    // weight conversions
    convert_f16<<<2048, 256, 0, stream>>>(w1, w1F, HID * FANIN / 4);
    convert_f16<<<1024, 256, 0, stream>>>(w2, w2F, HID * HID / 4);

    // RoIAlign: block per (channel, image, octant), 20.8 KB slab via DMA
    roi_align_kernel<<<dim3(CCH, 4, 8), 256, 0, stream>>>(
        x, geomD, cnt, cropsF);

    // FC1: K = 12544
    gemm_f16<<<dim3(HID / 128, NROI / 128, Z1), 256, 0, stream>>>(
        cropsF, w1F, P, NROI, HID, FANIN, FANIN / Z1);
    combine_relu_f16<<<(NROI * HID / 4) / 256, 256, 0, stream>>>(P, Z1, b1, h1F);

    // FC2: K = 1024
    gemm_f16<<<dim3(HID / 128, NROI / 128, Z2), 256, 0, stream>>>(
        h1F, w2F, P, NROI, HID, HID, HID / Z2);
    combine_relu_f32<<<(NROI * HID / 4) / 256, 256, 0, stream>>>(P, Z2, b2, h2);

    // heads
    heads_kernel<<<NROI / 4, 256, 0, stream>>>(h2, wc, bc, wb, bb, out);
}

// Round 14
// 262.030 us; speedup vs baseline: 1.0389x; 1.0389x over previous
//
#include <hip/hip_runtime.h>

#define NROI  2048
#define CCH   256
#define IMH   200
#define IMW   200
#define CROP  7
#define PP    49
#define FANIN 12544
#define HID   1024
#define OCTR  25                  // rows per octant
#define SLR   26                  // staged rows (incl guard)
#define SLAB  5208                // slab floats per buffer (>= 26*200+1, 8-mult)

typedef _Float16 f16x8 __attribute__((ext_vector_type(8)));
typedef _Float16 f16x4 __attribute__((ext_vector_type(4)));
typedef __attribute__((ext_vector_type(4))) float f32x4;

__device__ __forceinline__ void gload16(const void* g, void* l) {
    __builtin_amdgcn_global_load_lds(
        (const __attribute__((address_space(1))) void*)g,
        (__attribute__((address_space(3))) void*)l, 16, 0, 0);
}

// ---------------------------------------------------------------------------
// zero the 32 per-(image,octant) counters (ws not re-poisoned between replays)
// ---------------------------------------------------------------------------
__global__ void zero_cnt_kernel(int* __restrict__ cnt) {
    if (threadIdx.x < 32) cnt[threadIdx.x] = 0;
}

// ---------------------------------------------------------------------------
// Geometry binned by y-octant. One thread per ROI; per bin-row i append 7
// packed samples to the (image b, octant q=y0/25) dense list:
//   { x0 | y0rel<<8 | dx<<16 | dy<<17, wx, wy, n*FANIN + i*7 + j }.
// ---------------------------------------------------------------------------
__global__ __launch_bounds__(256) void roi_geom_kernel(
    const float* __restrict__ rois, uint4* __restrict__ geomD,
    int* __restrict__ cnt)
{
    const int n = blockIdx.x * 256 + threadIdx.x;
    if (n >= NROI) return;

    const int b = (int)rois[(size_t)n * 5 + 0];
    const float rx1 = rois[(size_t)n * 5 + 1];
    const float ry1 = rois[(size_t)n * 5 + 2];
    const float rx2 = rois[(size_t)n * 5 + 3];
    const float ry2 = rois[(size_t)n * 5 + 4];
    const float bw = (rx2 - rx1) / 7.0f;
    const float bh = (ry2 - ry1) / 7.0f;

    unsigned xbits[7]; unsigned xw[7];
#pragma unroll
    for (int j = 0; j < 7; ++j) {
        float px = __fadd_rn(rx1, __fmul_rn((float)j + 0.5f, bw));
        px = fminf(fmaxf(px, 0.0f), (float)(IMW - 1));
        const float fx = floorf(px);
        const int x0 = (int)fx;
        const int dx = min(x0 + 1, IMW - 1) - x0;
        xbits[j] = (unsigned)x0 | ((unsigned)dx << 16);
        xw[j] = __float_as_uint(px - fx);
    }

#pragma unroll
    for (int i = 0; i < 7; ++i) {
        float py = __fadd_rn(ry1, __fmul_rn((float)i + 0.5f, bh));
        py = fminf(fmaxf(py, 0.0f), (float)(IMH - 1));
        const float fy = floorf(py);
        const int y0 = (int)fy;
        const int dy = min(y0 + 1, IMH - 1) - y0;
        const unsigned wy = __float_as_uint(py - fy);
        const int q = y0 / OCTR;                    // 0..7
        const int y0r = y0 - q * OCTR;              // 0..24
        const unsigned ybits = ((unsigned)y0r << 8) | ((unsigned)dy << 17);

        const int base = atomicAdd(&cnt[b * 8 + q], 7);
        uint4* dst = geomD + (size_t)(b * 8 + q) * (NROI * PP) + base;
#pragma unroll
        for (int j = 0; j < 7; ++j)
            dst[j] = make_uint4(xbits[j] | ybits, xw[j], wy,
                                (unsigned)(n * FANIN + i * 7 + j));
    }
}

// ---------------------------------------------------------------------------
// RoIAlign, in-block pipelined: block = (c, b, half). Handles 4 octants with
// double-buffered 20.8 KB f32 slabs: issue next octant's global_load_lds
// BEFORE sweeping current (loads fly under the sweep; drained by the barrier
// after it). Paired corner reads -> ds_read2_b32; border via select.
// ---------------------------------------------------------------------------
__global__ __launch_bounds__(256) void roi_align_kernel(
    const float* __restrict__ x, const uint4* __restrict__ geomD,
    const int* __restrict__ cnt, _Float16* __restrict__ crops)
{
    __shared__ float slab[2][SLAB];                // 41,664 B -> 3 blocks/CU

    const int c  = blockIdx.x;
    const int b  = blockIdx.y;
    const int qb = blockIdx.z * 4;                 // 0 or 4
    const int tid = threadIdx.x;
    const int cOff = c * PP;
    const float* chbase = x + (size_t)(b * CCH + c) * (IMH * IMW);

    auto stage = [&](int buf, int q) {
        const char* src = (const char*)(chbase + (size_t)q * OCTR * IMW);
        char* dst = (char*)slab[buf];
        const int t16 = ((q == 7) ? OCTR : SLR) * 50;   // 16B chunks
        for (int t = tid; t < t16; t += 256)
            gload16(src + t * 16, dst + t * 16);
    };

    stage(0, qb);
    __syncthreads();                               // drain first stage

#pragma unroll
    for (int k = 0; k < 4; ++k) {
        const int q = qb + k;
        const int S = cnt[b * 8 + q];
        const uint4* gD = geomD + (size_t)(b * 8 + q) * (NROI * PP);

        // hoist first geometry entry BEFORE issuing next stage (so its
        // vmcnt wait does not drain the DMA queue)
        uint4 g = make_uint4(0, 0, 0, 0);
        if (tid < S) g = gD[tid];

        if (k < 3) stage((k + 1) & 1, qb + k + 1); // async, flies under sweep

        // ---- sweep octant q from slab[k&1] ----
        const float* sb = slab[k & 1];
        if (tid < S) {
            int s = tid;
            while (true) {
                const int sn = s + 256;
                const bool more = sn < S;
                uint4 gn = g;
                if (more) gn = gD[sn];

                const unsigned w0 = g.x;
                const int a00 = (int)((w0 >> 8) & 31) * IMW + (int)(w0 & 255);
                const int a10 = a00 + ((int)(w0 >> 17) & 1) * IMW;
                float v00 = sb[a00], v01 = sb[a00 + 1];   // ds_read2_b32
                float v10 = sb[a10], v11 = sb[a10 + 1];   // ds_read2_b32
                if (!((w0 >> 16) & 1)) { v01 = v00; v11 = v10; }
                const float wx = __uint_as_float(g.y);
                const float wy = __uint_as_float(g.z);
                const float top = v00 + wx * (v01 - v00);
                const float bot = v10 + wx * (v11 - v10);
                crops[g.w + cOff] = (_Float16)(top + wy * (bot - top));

                if (!more) break;
                s = sn; g = gn;
            }
        }
        __syncthreads();   // sweep done + next stage's DMA drained
    }
}

// ---------------------------------------------------------------------------
// f32 -> f16 weight conversion, vectorized (4 elems/thread).
// ---------------------------------------------------------------------------
__global__ __launch_bounds__(256) void convert_f16(
    const float* __restrict__ w, _Float16* __restrict__ wF, int n4)
{
    for (int g = blockIdx.x * 256 + threadIdx.x; g < n4; g += gridDim.x * 256) {
        const float4 v = ((const float4*)w)[g];
        f16x4 o = {(_Float16)v.x, (_Float16)v.y, (_Float16)v.z, (_Float16)v.w};
        ((f16x4*)wF)[g] = o;
    }
}

// ---------------------------------------------------------------------------
// f16 MFMA GEMM (NT), BK=64: P[z] = A[M,K] * B[N,K]^T over K-slice z.
// 128x128 tile, 4 waves of 64x64; 32 MFMA per barrier-pair.
// ---------------------------------------------------------------------------
__global__ __launch_bounds__(256, 3) void gemm_f16(
    const _Float16* __restrict__ A, const _Float16* __restrict__ B,
    float* __restrict__ P, int M, int N, int K, int kLen)
{
    __shared__ _Float16 lds[2][128][64];   // A, B tiles (16 KB each)

    const int tid  = threadIdx.x;
    const int wave = tid >> 6;
    const int lane = tid & 63;
    const int bm = blockIdx.y * 128;
    const int bn = blockIdx.x * 128;
    const int kBase = blockIdx.z * kLen;
    const int wr = wave >> 1, wc = wave & 1;

    f32x4 acc[4][4];
#pragma unroll
    for (int i = 0; i < 4; ++i)
#pragma unroll
        for (int j = 0; j < 4; ++j) acc[i][j] = (f32x4){0.f, 0.f, 0.f, 0.f};

    const int r_st = wave * 32 + (lane >> 3);
    const int s_st = ((lane & 7) ^ ((lane >> 4) & 3)) * 8;   // f16 units
    const _Float16* gA = A + (size_t)(bm + r_st) * K + kBase + s_st;
    const _Float16* gB = B + (size_t)(bn + r_st) * K + kBase + s_st;
    const size_t rstep8 = (size_t)8 * K;
    _Float16* lA = &lds[0][wave * 32][0];
    _Float16* lB = &lds[1][wave * 32][0];

    const int li = lane & 15;
    const int hi = lane >> 4;            // 0..3
    const int swb = (li >> 1) & 3;       // row-pair xor term

    for (int kt = 0; kt < kLen; kt += 64) {
#pragma unroll
        for (int ck = 0; ck < 4; ++ck) {
            gload16(gA + kt + ck * rstep8, lA + ck * 512);
            gload16(gB + kt + ck * rstep8, lB + ck * 512);
        }
        __syncthreads();

#pragma unroll
        for (int kk = 0; kk < 2; ++kk) {
            const int sw = (((kk << 2) | hi) ^ swb) * 8;     // f16 offset
            f16x8 a[4], b[4];
#pragma unroll
            for (int m = 0; m < 4; ++m)
                a[m] = *(const f16x8*)&lds[0][wr * 64 + m * 16 + li][sw];
#pragma unroll
            for (int n = 0; n < 4; ++n)
                b[n] = *(const f16x8*)&lds[1][wc * 64 + n * 16 + li][sw];
#pragma unroll
            for (int m = 0; m < 4; ++m)
#pragma unroll
                for (int n = 0; n < 4; ++n)
                    acc[m][n] = __builtin_amdgcn_mfma_f32_16x16x32_f16(a[m], b[n], acc[m][n], 0, 0, 0);
        }
        __syncthreads();
    }

    float* Pz = P + (size_t)blockIdx.z * M * N;
#pragma unroll
    for (int m = 0; m < 4; ++m)
#pragma unroll
        for (int n = 0; n < 4; ++n) {
            const int col = bn + wc * 64 + n * 16 + li;
#pragma unroll
            for (int e = 0; e < 4; ++e) {
                const int row = bm + wr * 64 + m * 16 + hi * 4 + e;
                Pz[(size_t)row * N + col] = acc[m][n][e];
            }
        }
}

// ---------------------------------------------------------------------------
// relu(sum_z P[z] + bias) -> f16
// ---------------------------------------------------------------------------
__global__ __launch_bounds__(256) void combine_relu_f16(
    const float* __restrict__ P, int Z, const float* __restrict__ bias,
    _Float16* __restrict__ H)
{
    const int g = blockIdx.x * 256 + threadIdx.x;
    const size_t MN4 = (size_t)NROI * HID / 4;
    float4 s = ((const float4*)P)[g];
    for (int z = 1; z < Z; ++z) {
        const float4 p = ((const float4*)P)[z * MN4 + g];
        s.x += p.x; s.y += p.y; s.z += p.z; s.w += p.w;
    }
    const float4 bv = *(const float4*)(bias + (g & 255) * 4);
    f16x4 o = {(_Float16)fmaxf(s.x + bv.x, 0.0f),
               (_Float16)fmaxf(s.y + bv.y, 0.0f),
               (_Float16)fmaxf(s.z + bv.z, 0.0f),
               (_Float16)fmaxf(s.w + bv.w, 0.0f)};
    ((f16x4*)H)[g] = o;
}

// ---------------------------------------------------------------------------
// relu(sum_z P[z] + bias) -> f32 (aliases P[0] elementwise - safe)
// ---------------------------------------------------------------------------
__global__ __launch_bounds__(256) void combine_relu_f32(
    const float* __restrict__ P, int Z, const float* __restrict__ bias,
    float* __restrict__ H)
{
    const int g = blockIdx.x * 256 + threadIdx.x;
    const size_t MN4 = (size_t)NROI * HID / 4;
    float4 s = ((const float4*)P)[g];
    for (int z = 1; z < Z; ++z) {
        const float4 p = ((const float4*)P)[z * MN4 + g];
        s.x += p.x; s.y += p.y; s.z += p.z; s.w += p.w;
    }
    const float4 bv = *(const float4*)(bias + (g & 255) * 4);
    float4 r;
    r.x = fmaxf(s.x + bv.x, 0.0f);
    r.y = fmaxf(s.y + bv.y, 0.0f);
    r.z = fmaxf(s.z + bv.z, 0.0f);
    r.w = fmaxf(s.w + bv.w, 0.0f);
    ((float4*)H)[g] = r;
}

// ---------------------------------------------------------------------------
// heads: one wave per ROI row; 10 dots of K=1024, shfl_xor reduce.
// ---------------------------------------------------------------------------
__global__ __launch_bounds__(256) void heads_kernel(
    const float* __restrict__ h2,
    const float* __restrict__ wc, const float* __restrict__ bc,
    const float* __restrict__ wb, const float* __restrict__ bb,
    float* __restrict__ out)
{
    const int gw   = (blockIdx.x * 256 + threadIdx.x) >> 6;
    const int lane = threadIdx.x & 63;
    const float* hrow = h2 + (size_t)gw * HID;

    float4 h[4];
#pragma unroll
    for (int j = 0; j < 4; ++j)
        h[j] = *(const float4*)(hrow + lane * 16 + j * 4);

    float keep = 0.0f;
#pragma unroll
    for (int o = 0; o < 10; ++o) {
        const float* wrow = (o < 2) ? (wc + (size_t)o * HID)
                                    : (wb + (size_t)(o - 2) * HID);
        float acc = 0.0f;
#pragma unroll
        for (int j = 0; j < 4; ++j) {
            const float4 w4 = *(const float4*)(wrow + lane * 16 + j * 4);
            acc += h[j].x * w4.x + h[j].y * w4.y + h[j].z * w4.z + h[j].w * w4.w;
        }
#pragma unroll
        for (int s = 32; s; s >>= 1) acc += __shfl_xor(acc, s, 64);
        if (lane == o) keep = acc;
    }
    if (lane < 2)        out[gw * 2 + lane] = keep + bc[lane];
    else if (lane < 10)  out[NROI * 2 + gw * 8 + (lane - 2)] = keep + bb[lane - 2];
}

// ---------------------------------------------------------------------------
extern "C" void kernel_launch(void* const* d_in, const int* in_sizes, int n_in,
                              void* d_out, int out_size, void* d_ws, size_t ws_size,
                              hipStream_t stream)
{
    const float* x    = (const float*)d_in[0];
    const float* rois = (const float*)d_in[1];
    const float* w1   = (const float*)d_in[2];
    const float* b1   = (const float*)d_in[3];
    const float* w2   = (const float*)d_in[4];
    const float* b2   = (const float*)d_in[5];
    const float* wc   = (const float*)d_in[6];
    const float* bc   = (const float*)d_in[7];
    const float* wb   = (const float*)d_in[8];
    const float* bb   = (const float*)d_in[9];
    float* out = (float*)d_out;

    char* ws = (char*)d_ws;
    const size_t CRB = (size_t)NROI * FANIN * 2;       // 51,380,224
    const size_t W1B = (size_t)HID * FANIN * 2;        // 25,690,112
    const size_t W2B = (size_t)HID * HID * 2;          //  2,097,152
    const size_t PB  = (size_t)NROI * HID * 4;         //  8,388,608 per z-slice
    const size_t HB  = (size_t)NROI * HID * 2;         //  4,194,304
    const size_t GDB = (size_t)32 * NROI * PP * 16;    // 51,380,224

    const int Z1 = 7;   // FC1 K-split: 12544/7 = 1792 = 28 x 64
    const int Z2 = 4;   // FC2 K-split: 1024/4  = 256 =  4 x 64

    size_t off = 0;
    _Float16* cropsF = (_Float16*)(ws + off); off += CRB;
    _Float16* w1F    = (_Float16*)(ws + off); off += W1B;
    _Float16* w2F    = (_Float16*)(ws + off); off += W2B;
    float*    P      = (float*)(ws + off);    off += (size_t)Z1 * PB;
    _Float16* h1F    = (_Float16*)(ws + off); off += HB;
    uint4*    geomD  = (uint4*)(ws + off);    off += GDB;
    int*      cnt    = (int*)(ws + off);      off += 128;
    float*    h2     = P;   // elementwise alias with P[0] in combine_relu_f32

    // geometry binned by (image, y-octant)
    zero_cnt_kernel<<<1, 64, 0, stream>>>(cnt);
    roi_geom_kernel<<<NROI / 256, 256, 0, stream>>>(rois, geomD, cnt);

    // weight conversions
    convert_f16<<<2048, 256, 0, stream>>>(w1, w1F, HID * FANIN / 4);
    convert_f16<<<1024, 256, 0, stream>>>(w2, w2F, HID * HID / 4);

    // RoIAlign: block per (channel, image, image-half), pipelined octants
    roi_align_kernel<<<dim3(CCH, 4, 2), 256, 0, stream>>>(
        x, geomD, cnt, cropsF);

    // FC1: K = 12544
    gemm_f16<<<dim3(HID / 128, NROI / 128, Z1), 256, 0, stream>>>(
        cropsF, w1F, P, NROI, HID, FANIN, FANIN / Z1);
    combine_relu_f16<<<(NROI * HID / 4) / 256, 256, 0, stream>>>(P, Z1, b1, h1F);

    // FC2: K = 1024
    gemm_f16<<<dim3(HID / 128, NROI / 128, Z2), 256, 0, stream>>>(
        h1F, w2F, P, NROI, HID, HID, HID / Z2);
    combine_relu_f32<<<(NROI * HID / 4) / 256, 256, 0, stream>>>(P, Z2, b2, h2);

    // heads
    heads_kernel<<<NROI / 4, 256, 0, stream>>>(h2, wc, bc, wb, bb, out);
}

// Round 15
// 244.086 us; speedup vs baseline: 1.1153x; 1.0735x over previous
//
#include <hip/hip_runtime.h>

#define NROI  2048
#define CCH   256
#define IMH   200
#define IMW   200
#define CROP  7
#define PP    49
#define FANIN 12544
#define HID   1024

typedef _Float16 f16x8 __attribute__((ext_vector_type(8)));
typedef _Float16 f16x4 __attribute__((ext_vector_type(4)));
typedef __attribute__((ext_vector_type(4))) float f32x4;

__device__ __forceinline__ void gload16(const void* g, void* l) {
    __builtin_amdgcn_global_load_lds(
        (const __attribute__((address_space(1))) void*)g,
        (__attribute__((address_space(3))) void*)l, 16, 0, 0);
}

// ---------------------------------------------------------------------------
// Transpose+convert: x[b][c][h][w] f32 -> xT[b][h][w][c] f16.
// Block = (half, h, b): 256 threads, thread=channel reads 100 w (25 float4,
// 400-B runs), LDS tile [100][258], then 512-B coalesced vector writes.
// ---------------------------------------------------------------------------
__global__ __launch_bounds__(256) void transpose_f16(
    const float* __restrict__ x, _Float16* __restrict__ xT)
{
    __shared__ _Float16 t[100][258];   // 51,600 B -> 3 blocks/CU

    const int half = blockIdx.x;       // 0,1
    const int h    = blockIdx.y;       // 0..199
    const int b    = blockIdx.z;       // 0..3
    const int c    = threadIdx.x;      // 0..255

    // ---- read: channel c's 100-float run, convert, scatter into LDS ----
    const float* src = x + ((size_t)(b * CCH + c) * IMH + h) * IMW + half * 100;
#pragma unroll
    for (int i = 0; i < 25; ++i) {
        const float4 v = *(const float4*)(src + i * 4);
        t[i * 4 + 0][c] = (_Float16)v.x;
        t[i * 4 + 1][c] = (_Float16)v.y;
        t[i * 4 + 2][c] = (_Float16)v.z;
        t[i * 4 + 3][c] = (_Float16)v.w;
    }
    __syncthreads();

    // ---- write: 8 w per round, 32 lanes x 16 B per w ----
    _Float16* dst = xT + ((size_t)(b * IMH + h) * IMW + half * 100) * CCH;
    const int wq = threadIdx.x >> 5;          // 0..7
    const int l32 = threadIdx.x & 31;
#pragma unroll
    for (int r = 0; r < 13; ++r) {
        const int w = r * 8 + wq;
        if (w < 100)
            *(f16x8*)(dst + (size_t)w * CCH + l32 * 8) =
                *(const f16x8*)&t[w][l32 * 8];
    }
}

// ---------------------------------------------------------------------------
// RoIAlign gather: block = ROI n, 4 waves; wave processes sample p (p=wave,
// wave+4,...): geometry computed inline (wave-uniform), 4 coalesced 512-B
// corner-vector loads from xT, bilinear blend, 512-B store.
// Crops K-order: k' = p*256 + c  (w1 permuted identically).
// ---------------------------------------------------------------------------
__global__ __launch_bounds__(256) void roi_gather_kernel(
    const _Float16* __restrict__ xT, const float* __restrict__ rois,
    _Float16* __restrict__ crops)
{
    const int n    = blockIdx.x;
    const int wave = threadIdx.x >> 6;
    const int lane = threadIdx.x & 63;

    const int   b   = (int)rois[(size_t)n * 5 + 0];
    const float rx1 = rois[(size_t)n * 5 + 1];
    const float ry1 = rois[(size_t)n * 5 + 2];
    const float rx2 = rois[(size_t)n * 5 + 3];
    const float ry2 = rois[(size_t)n * 5 + 4];
    const float bw = (rx2 - rx1) / 7.0f;
    const float bh = (ry2 - ry1) / 7.0f;

    const _Float16* xb = xT + (size_t)b * (IMH * IMW * CCH);
    _Float16* crow = crops + (size_t)n * FANIN;

    for (int p = wave; p < PP; p += 4) {
        const int i = p / 7;           // bin row -> y
        const int j = p - i * 7;       // bin col -> x
        float px = __fadd_rn(rx1, __fmul_rn((float)j + 0.5f, bw));
        float py = __fadd_rn(ry1, __fmul_rn((float)i + 0.5f, bh));
        px = fminf(fmaxf(px, 0.0f), (float)(IMW - 1));
        py = fminf(fmaxf(py, 0.0f), (float)(IMH - 1));
        const float fx = floorf(px), fy = floorf(py);
        const int x0 = (int)fx, y0 = (int)fy;
        const int dxo = (min(x0 + 1, IMW - 1) - x0) * CCH;
        const int dyo = (min(y0 + 1, IMH - 1) - y0) * (IMW * CCH);
        const float wx = px - fx, wy = py - fy;

        const _Float16* cb = xb + (size_t)(y0 * IMW + x0) * CCH + lane * 4;
        const f16x4 A = *(const f16x4*)(cb);
        const f16x4 B = *(const f16x4*)(cb + dxo);
        const f16x4 C = *(const f16x4*)(cb + dyo);
        const f16x4 D = *(const f16x4*)(cb + dyo + dxo);

        f16x4 o;
#pragma unroll
        for (int e = 0; e < 4; ++e) {
            const float v00 = (float)A[e], v01 = (float)B[e];
            const float v10 = (float)C[e], v11 = (float)D[e];
            const float top = v00 + wx * (v01 - v00);
            const float bot = v10 + wx * (v11 - v10);
            o[e] = (_Float16)(top + wy * (bot - top));
        }
        *(f16x4*)(crow + p * CCH + lane * 4) = o;
    }
}

// ---------------------------------------------------------------------------
// w1 permute+convert: w1P[o][p*256+c] = (f16) w1[o][c*49+p].
// Block per output row o: stage row in LDS (coalesced), write permuted
// (coalesced 512-B stores; LDS gather ~4-way conflicts, cheap).
// ---------------------------------------------------------------------------
__global__ __launch_bounds__(256) void permute_w1_kernel(
    const float* __restrict__ w1, _Float16* __restrict__ w1P)
{
    __shared__ _Float16 row[FANIN];    // 25,088 B

    const int o   = blockIdx.x;
    const int tid = threadIdx.x;
    const float* src = w1 + (size_t)o * FANIN;

    for (int g = tid; g < FANIN / 4; g += 256) {
        const float4 v = *(const float4*)(src + g * 4);
        f16x4 f = {(_Float16)v.x, (_Float16)v.y, (_Float16)v.z, (_Float16)v.w};
        *(f16x4*)&row[g * 4] = f;
    }
    __syncthreads();

    _Float16* dst = w1P + (size_t)o * FANIN;
    for (int g = tid; g < FANIN; g += 256) {
        const int p = g >> 8;          // 0..48
        const int c = g & 255;
        dst[g] = row[c * PP + p];
    }
}

// ---------------------------------------------------------------------------
// f32 -> f16 conversion (w2), vectorized.
// ---------------------------------------------------------------------------
__global__ __launch_bounds__(256) void convert_f16(
    const float* __restrict__ w, _Float16* __restrict__ wF, int n4)
{
    for (int g = blockIdx.x * 256 + threadIdx.x; g < n4; g += gridDim.x * 256) {
        const float4 v = ((const float4*)w)[g];
        f16x4 o = {(_Float16)v.x, (_Float16)v.y, (_Float16)v.z, (_Float16)v.w};
        ((f16x4*)wF)[g] = o;
    }
}

// ---------------------------------------------------------------------------
// f16 MFMA GEMM (NT), BK=64: P[z] = A[M,K] * B[N,K]^T over K-slice z.
// 128x128 tile, 4 waves of 64x64; 32 MFMA per barrier-pair.
// ---------------------------------------------------------------------------
__global__ __launch_bounds__(256, 3) void gemm_f16(
    const _Float16* __restrict__ A, const _Float16* __restrict__ B,
    float* __restrict__ P, int M, int N, int K, int kLen)
{
    __shared__ _Float16 lds[2][128][64];   // A, B tiles (16 KB each)

    const int tid  = threadIdx.x;
    const int wave = tid >> 6;
    const int lane = tid & 63;
    const int bm = blockIdx.y * 128;
    const int bn = blockIdx.x * 128;
    const int kBase = blockIdx.z * kLen;
    const int wr = wave >> 1, wc = wave & 1;

    f32x4 acc[4][4];
#pragma unroll
    for (int i = 0; i < 4; ++i)
#pragma unroll
        for (int j = 0; j < 4; ++j) acc[i][j] = (f32x4){0.f, 0.f, 0.f, 0.f};

    const int r_st = wave * 32 + (lane >> 3);
    const int s_st = ((lane & 7) ^ ((lane >> 4) & 3)) * 8;   // f16 units
    const _Float16* gA = A + (size_t)(bm + r_st) * K + kBase + s_st;
    const _Float16* gB = B + (size_t)(bn + r_st) * K + kBase + s_st;
    const size_t rstep8 = (size_t)8 * K;
    _Float16* lA = &lds[0][wave * 32][0];
    _Float16* lB = &lds[1][wave * 32][0];

    const int li = lane & 15;
    const int hi = lane >> 4;            // 0..3
    const int swb = (li >> 1) & 3;       // row-pair xor term

    for (int kt = 0; kt < kLen; kt += 64) {
#pragma unroll
        for (int ck = 0; ck < 4; ++ck) {
            gload16(gA + kt + ck * rstep8, lA + ck * 512);
            gload16(gB + kt + ck * rstep8, lB + ck * 512);
        }
        __syncthreads();

#pragma unroll
        for (int kk = 0; kk < 2; ++kk) {
            const int sw = (((kk << 2) | hi) ^ swb) * 8;     // f16 offset
            f16x8 a[4], b[4];
#pragma unroll
            for (int m = 0; m < 4; ++m)
                a[m] = *(const f16x8*)&lds[0][wr * 64 + m * 16 + li][sw];
#pragma unroll
            for (int n = 0; n < 4; ++n)
                b[n] = *(const f16x8*)&lds[1][wc * 64 + n * 16 + li][sw];
#pragma unroll
            for (int m = 0; m < 4; ++m)
#pragma unroll
                for (int n = 0; n < 4; ++n)
                    acc[m][n] = __builtin_amdgcn_mfma_f32_16x16x32_f16(a[m], b[n], acc[m][n], 0, 0, 0);
        }
        __syncthreads();
    }

    float* Pz = P + (size_t)blockIdx.z * M * N;
#pragma unroll
    for (int m = 0; m < 4; ++m)
#pragma unroll
        for (int n = 0; n < 4; ++n) {
            const int col = bn + wc * 64 + n * 16 + li;
#pragma unroll
            for (int e = 0; e < 4; ++e) {
                const int row = bm + wr * 64 + m * 16 + hi * 4 + e;
                Pz[(size_t)row * N + col] = acc[m][n][e];
            }
        }
}

// ---------------------------------------------------------------------------
// relu(sum_z P[z] + bias) -> f16
// ---------------------------------------------------------------------------
__global__ __launch_bounds__(256) void combine_relu_f16(
    const float* __restrict__ P, int Z, const float* __restrict__ bias,
    _Float16* __restrict__ H)
{
    const int g = blockIdx.x * 256 + threadIdx.x;
    const size_t MN4 = (size_t)NROI * HID / 4;
    float4 s = ((const float4*)P)[g];
    for (int z = 1; z < Z; ++z) {
        const float4 p = ((const float4*)P)[z * MN4 + g];
        s.x += p.x; s.y += p.y; s.z += p.z; s.w += p.w;
    }
    const float4 bv = *(const float4*)(bias + (g & 255) * 4);
    f16x4 o = {(_Float16)fmaxf(s.x + bv.x, 0.0f),
               (_Float16)fmaxf(s.y + bv.y, 0.0f),
               (_Float16)fmaxf(s.z + bv.z, 0.0f),
               (_Float16)fmaxf(s.w + bv.w, 0.0f)};
    ((f16x4*)H)[g] = o;
}

// ---------------------------------------------------------------------------
// relu(sum_z P[z] + bias) -> f32 (aliases P[0] elementwise - safe)
// ---------------------------------------------------------------------------
__global__ __launch_bounds__(256) void combine_relu_f32(
    const float* __restrict__ P, int Z, const float* __restrict__ bias,
    float* __restrict__ H)
{
    const int g = blockIdx.x * 256 + threadIdx.x;
    const size_t MN4 = (size_t)NROI * HID / 4;
    float4 s = ((const float4*)P)[g];
    for (int z = 1; z < Z; ++z) {
        const float4 p = ((const float4*)P)[z * MN4 + g];
        s.x += p.x; s.y += p.y; s.z += p.z; s.w += p.w;
    }
    const float4 bv = *(const float4*)(bias + (g & 255) * 4);
    float4 r;
    r.x = fmaxf(s.x + bv.x, 0.0f);
    r.y = fmaxf(s.y + bv.y, 0.0f);
    r.z = fmaxf(s.z + bv.z, 0.0f);
    r.w = fmaxf(s.w + bv.w, 0.0f);
    ((float4*)H)[g] = r;
}

// ---------------------------------------------------------------------------
// heads: one wave per ROI row; 10 dots of K=1024, shfl_xor reduce.
// ---------------------------------------------------------------------------
__global__ __launch_bounds__(256) void heads_kernel(
    const float* __restrict__ h2,
    const float* __restrict__ wc, const float* __restrict__ bc,
    const float* __restrict__ wb, const float* __restrict__ bb,
    float* __restrict__ out)
{
    const int gw   = (blockIdx.x * 256 + threadIdx.x) >> 6;
    const int lane = threadIdx.x & 63;
    const float* hrow = h2 + (size_t)gw * HID;

    float4 h[4];
#pragma unroll
    for (int j = 0; j < 4; ++j)
        h[j] = *(const float4*)(hrow + lane * 16 + j * 4);

    float keep = 0.0f;
#pragma unroll
    for (int o = 0; o < 10; ++o) {
        const float* wrow = (o < 2) ? (wc + (size_t)o * HID)
                                    : (wb + (size_t)(o - 2) * HID);
        float acc = 0.0f;
#pragma unroll
        for (int j = 0; j < 4; ++j) {
            const float4 w4 = *(const float4*)(wrow + lane * 16 + j * 4);
            acc += h[j].x * w4.x + h[j].y * w4.y + h[j].z * w4.z + h[j].w * w4.w;
        }
#pragma unroll
        for (int s = 32; s; s >>= 1) acc += __shfl_xor(acc, s, 64);
        if (lane == o) keep = acc;
    }
    if (lane < 2)        out[gw * 2 + lane] = keep + bc[lane];
    else if (lane < 10)  out[NROI * 2 + gw * 8 + (lane - 2)] = keep + bb[lane - 2];
}

// ---------------------------------------------------------------------------
extern "C" void kernel_launch(void* const* d_in, const int* in_sizes, int n_in,
                              void* d_out, int out_size, void* d_ws, size_t ws_size,
                              hipStream_t stream)
{
    const float* x    = (const float*)d_in[0];
    const float* rois = (const float*)d_in[1];
    const float* w1   = (const float*)d_in[2];
    const float* b1   = (const float*)d_in[3];
    const float* w2   = (const float*)d_in[4];
    const float* b2   = (const float*)d_in[5];
    const float* wc   = (const float*)d_in[6];
    const float* bc   = (const float*)d_in[7];
    const float* wb   = (const float*)d_in[8];
    const float* bb   = (const float*)d_in[9];
    float* out = (float*)d_out;

    char* ws = (char*)d_ws;
    const size_t CRB = (size_t)NROI * FANIN * 2;       // 51,380,224
    const size_t W1B = (size_t)HID * FANIN * 2;        // 25,690,112
    const size_t W2B = (size_t)HID * HID * 2;          //  2,097,152
    const size_t PB  = (size_t)NROI * HID * 4;         //  8,388,608 per z-slice
    const size_t HB  = (size_t)NROI * HID * 2;         //  4,194,304
    const size_t XTB = (size_t)4 * IMH * IMW * CCH * 2;// 81,920,000

    const int Z1 = 7;   // FC1 K-split: 12544/7 = 1792 = 28 x 64
    const int Z2 = 4;   // FC2 K-split: 1024/4  = 256 =  4 x 64

    size_t off = 0;
    _Float16* cropsP = (_Float16*)(ws + off); off += CRB;
    _Float16* w1P    = (_Float16*)(ws + off); off += W1B;
    _Float16* w2F    = (_Float16*)(ws + off); off += W2B;
    float*    P      = (float*)(ws + off);    off += (size_t)Z1 * PB;
    _Float16* h1F    = (_Float16*)(ws + off); off += HB;
    _Float16* xT     = (_Float16*)(ws + off); off += XTB;   // total ~224 MB
    float*    h2     = P;   // elementwise alias with P[0] in combine_relu_f32

    // weight prep
    permute_w1_kernel<<<HID, 256, 0, stream>>>(w1, w1P);
    convert_f16<<<1024, 256, 0, stream>>>(w2, w2F, HID * HID / 4);

    // x -> xT (f16, channel-last)
    transpose_f16<<<dim3(2, IMH, 4), 256, 0, stream>>>(x, xT);

    // RoIAlign gather: block per ROI, wave per sample
    roi_gather_kernel<<<NROI, 256, 0, stream>>>(xT, rois, cropsP);

    // FC1: K = 12544 (K-order p*256+c on both operands)
    gemm_f16<<<dim3(HID / 128, NROI / 128, Z1), 256, 0, stream>>>(
        cropsP, w1P, P, NROI, HID, FANIN, FANIN / Z1);
    combine_relu_f16<<<(NROI * HID / 4) / 256, 256, 0, stream>>>(P, Z1, b1, h1F);

    // FC2: K = 1024
    gemm_f16<<<dim3(HID / 128, NROI / 128, Z2), 256, 0, stream>>>(
        h1F, w2F, P, NROI, HID, HID, HID / Z2);
    combine_relu_f32<<<(NROI * HID / 4) / 256, 256, 0, stream>>>(P, Z2, b2, h2);

    // heads
    heads_kernel<<<NROI / 4, 256, 0, stream>>>(h2, wc, bc, wb, bb, out);
}

// Round 16
// 241.613 us; speedup vs baseline: 1.1267x; 1.0102x over previous
//
#include <hip/hip_runtime.h>

#define NROI  2048
#define CCH   256
#define IMH   200
#define IMW   200
#define CROP  7
#define PP    49
#define FANIN 12544
#define HID   1024

typedef _Float16 f16x8 __attribute__((ext_vector_type(8)));
typedef _Float16 f16x4 __attribute__((ext_vector_type(4)));
typedef __attribute__((ext_vector_type(4))) float f32x4;

__device__ __forceinline__ void gload16(const void* g, void* l) {
    __builtin_amdgcn_global_load_lds(
        (const __attribute__((address_space(1))) void*)g,
        (__attribute__((address_space(3))) void*)l, 16, 0, 0);
}

// ---------------------------------------------------------------------------
// Transpose+convert: x[b][c][h][w] f32 -> xT[b][h][w][c] f16.
// ---------------------------------------------------------------------------
__global__ __launch_bounds__(256) void transpose_f16(
    const float* __restrict__ x, _Float16* __restrict__ xT)
{
    __shared__ _Float16 t[100][258];   // 51,600 B -> 3 blocks/CU

    const int half = blockIdx.x;       // 0,1
    const int h    = blockIdx.y;       // 0..199
    const int b    = blockIdx.z;       // 0..3
    const int c    = threadIdx.x;      // 0..255

    const float* src = x + ((size_t)(b * CCH + c) * IMH + h) * IMW + half * 100;
#pragma unroll
    for (int i = 0; i < 25; ++i) {
        const float4 v = *(const float4*)(src + i * 4);
        t[i * 4 + 0][c] = (_Float16)v.x;
        t[i * 4 + 1][c] = (_Float16)v.y;
        t[i * 4 + 2][c] = (_Float16)v.z;
        t[i * 4 + 3][c] = (_Float16)v.w;
    }
    __syncthreads();

    _Float16* dst = xT + ((size_t)(b * IMH + h) * IMW + half * 100) * CCH;
    const int wq = threadIdx.x >> 5;          // 0..7
    const int l32 = threadIdx.x & 31;
#pragma unroll
    for (int r = 0; r < 13; ++r) {
        const int w = r * 8 + wq;
        if (w < 100)
            *(f16x8*)(dst + (size_t)w * CCH + l32 * 8) =
                *(const f16x8*)&t[w][l32 * 8];
    }
}

// ---------------------------------------------------------------------------
// RoIAlign gather: block = ROI n, 4 waves; wave = one sample across channels.
// Crops K-order: k' = p*256 + c  (w1 permuted identically).
// ---------------------------------------------------------------------------
__global__ __launch_bounds__(256) void roi_gather_kernel(
    const _Float16* __restrict__ xT, const float* __restrict__ rois,
    _Float16* __restrict__ crops)
{
    const int n    = blockIdx.x;
    const int wave = threadIdx.x >> 6;
    const int lane = threadIdx.x & 63;

    const int   b   = (int)rois[(size_t)n * 5 + 0];
    const float rx1 = rois[(size_t)n * 5 + 1];
    const float ry1 = rois[(size_t)n * 5 + 2];
    const float rx2 = rois[(size_t)n * 5 + 3];
    const float ry2 = rois[(size_t)n * 5 + 4];
    const float bw = (rx2 - rx1) / 7.0f;
    const float bh = (ry2 - ry1) / 7.0f;

    const _Float16* xb = xT + (size_t)b * (IMH * IMW * CCH);
    _Float16* crow = crops + (size_t)n * FANIN;

    for (int p = wave; p < PP; p += 4) {
        const int i = p / 7;           // bin row -> y
        const int j = p - i * 7;       // bin col -> x
        float px = __fadd_rn(rx1, __fmul_rn((float)j + 0.5f, bw));
        float py = __fadd_rn(ry1, __fmul_rn((float)i + 0.5f, bh));
        px = fminf(fmaxf(px, 0.0f), (float)(IMW - 1));
        py = fminf(fmaxf(py, 0.0f), (float)(IMH - 1));
        const float fx = floorf(px), fy = floorf(py);
        const int x0 = (int)fx, y0 = (int)fy;
        const int dxo = (min(x0 + 1, IMW - 1) - x0) * CCH;
        const int dyo = (min(y0 + 1, IMH - 1) - y0) * (IMW * CCH);
        const float wx = px - fx, wy = py - fy;

        const _Float16* cb = xb + (size_t)(y0 * IMW + x0) * CCH + lane * 4;
        const f16x4 A = *(const f16x4*)(cb);
        const f16x4 B = *(const f16x4*)(cb + dxo);
        const f16x4 C = *(const f16x4*)(cb + dyo);
        const f16x4 D = *(const f16x4*)(cb + dyo + dxo);

        f16x4 o;
#pragma unroll
        for (int e = 0; e < 4; ++e) {
            const float v00 = (float)A[e], v01 = (float)B[e];
            const float v10 = (float)C[e], v11 = (float)D[e];
            const float top = v00 + wx * (v01 - v00);
            const float bot = v10 + wx * (v11 - v10);
            o[e] = (_Float16)(top + wy * (bot - top));
        }
        *(f16x4*)(crow + p * CCH + lane * 4) = o;
    }
}

// ---------------------------------------------------------------------------
// w1 permute+convert: w1P[o][p*256+c] = (f16) w1[o][c*49+p].
// ---------------------------------------------------------------------------
__global__ __launch_bounds__(256) void permute_w1_kernel(
    const float* __restrict__ w1, _Float16* __restrict__ w1P)
{
    __shared__ _Float16 row[FANIN];    // 25,088 B

    const int o   = blockIdx.x;
    const int tid = threadIdx.x;
    const float* src = w1 + (size_t)o * FANIN;

    for (int g = tid; g < FANIN / 4; g += 256) {
        const float4 v = *(const float4*)(src + g * 4);
        f16x4 f = {(_Float16)v.x, (_Float16)v.y, (_Float16)v.z, (_Float16)v.w};
        *(f16x4*)&row[g * 4] = f;
    }
    __syncthreads();

    _Float16* dst = w1P + (size_t)o * FANIN;
    for (int g = tid; g < FANIN; g += 256) {
        const int p = g >> 8;          // 0..48
        const int c = g & 255;
        dst[g] = row[c * PP + p];
    }
}

// ---------------------------------------------------------------------------
// f32 -> f16 conversion (w2), vectorized.
// ---------------------------------------------------------------------------
__global__ __launch_bounds__(256) void convert_f16(
    const float* __restrict__ w, _Float16* __restrict__ wF, int n4)
{
    for (int g = blockIdx.x * 256 + threadIdx.x; g < n4; g += gridDim.x * 256) {
        const float4 v = ((const float4*)w)[g];
        f16x4 o = {(_Float16)v.x, (_Float16)v.y, (_Float16)v.z, (_Float16)v.w};
        ((f16x4*)wF)[g] = o;
    }
}

// ---------------------------------------------------------------------------
// FC1 GEMM (NT), 256x256 tile, BK=64, 8 waves (4M x 2N, wave = 64x128).
// Halves L3 operand traffic vs 128^2 (A x4, B x8 re-reads). Same verified
// XOR swizzle: LDS[row][s] holds global slot s ^ ((row>>1)&3); read slot
// (kk*4+hi) ^ ((li>>1)&3). All row bases are multiples of 8.
// ---------------------------------------------------------------------------
__global__ __launch_bounds__(512, 1) void gemm_f16_256(
    const _Float16* __restrict__ A, const _Float16* __restrict__ B,
    float* __restrict__ P, int M, int N, int K, int kLen)
{
    __shared__ _Float16 lds[2][256][64];   // A, B tiles (32 KB each)

    const int tid  = threadIdx.x;
    const int wave = tid >> 6;           // 0..7
    const int lane = tid & 63;
    const int bm = blockIdx.y * 256;
    const int bn = blockIdx.x * 256;
    const int kBase = blockIdx.z * kLen;
    const int wr = wave >> 1;            // 0..3 (M)
    const int wc = wave & 1;             // 0..1 (N)

    f32x4 acc[4][8];
#pragma unroll
    for (int i = 0; i < 4; ++i)
#pragma unroll
        for (int j = 0; j < 8; ++j) acc[i][j] = (f32x4){0.f, 0.f, 0.f, 0.f};

    // staging: wave covers rows [wave*32, wave*32+32) via 4 chunks of 8 rows
    const int r_st = wave * 32 + (lane >> 3);
    const int s_st = ((lane & 7) ^ ((lane >> 4) & 3)) * 8;   // f16 units
    const _Float16* gA = A + (size_t)(bm + r_st) * K + kBase + s_st;
    const _Float16* gB = B + (size_t)(bn + r_st) * K + kBase + s_st;
    const size_t rstep8 = (size_t)8 * K;
    _Float16* lA = &lds[0][wave * 32][0];
    _Float16* lB = &lds[1][wave * 32][0];

    const int li = lane & 15;
    const int hi = lane >> 4;            // 0..3
    const int swb = (li >> 1) & 3;       // row-pair xor term

    for (int kt = 0; kt < kLen; kt += 64) {
#pragma unroll
        for (int ck = 0; ck < 4; ++ck) {
            gload16(gA + kt + ck * rstep8, lA + ck * 512);
            gload16(gB + kt + ck * rstep8, lB + ck * 512);
        }
        __syncthreads();

#pragma unroll
        for (int kk = 0; kk < 2; ++kk) {
            const int sw = (((kk << 2) | hi) ^ swb) * 8;     // f16 offset
            f16x8 a[4], b[8];
#pragma unroll
            for (int m = 0; m < 4; ++m)
                a[m] = *(const f16x8*)&lds[0][wr * 64 + m * 16 + li][sw];
#pragma unroll
            for (int n = 0; n < 8; ++n)
                b[n] = *(const f16x8*)&lds[1][wc * 128 + n * 16 + li][sw];
#pragma unroll
            for (int m = 0; m < 4; ++m)
#pragma unroll
                for (int n = 0; n < 8; ++n)
                    acc[m][n] = __builtin_amdgcn_mfma_f32_16x16x32_f16(a[m], b[n], acc[m][n], 0, 0, 0);
        }
        __syncthreads();
    }

    float* Pz = P + (size_t)blockIdx.z * M * N;
#pragma unroll
    for (int m = 0; m < 4; ++m)
#pragma unroll
        for (int n = 0; n < 8; ++n) {
            const int col = bn + wc * 128 + n * 16 + li;
#pragma unroll
            for (int e = 0; e < 4; ++e) {
                const int row = bm + wr * 64 + m * 16 + hi * 4 + e;
                Pz[(size_t)row * N + col] = acc[m][n][e];
            }
        }
}

// ---------------------------------------------------------------------------
// FC2 GEMM (NT), 128x128 tile, BK=64 (proven r11 config).
// ---------------------------------------------------------------------------
__global__ __launch_bounds__(256, 3) void gemm_f16(
    const _Float16* __restrict__ A, const _Float16* __restrict__ B,
    float* __restrict__ P, int M, int N, int K, int kLen)
{
    __shared__ _Float16 lds[2][128][64];   // A, B tiles (16 KB each)

    const int tid  = threadIdx.x;
    const int wave = tid >> 6;
    const int lane = tid & 63;
    const int bm = blockIdx.y * 128;
    const int bn = blockIdx.x * 128;
    const int kBase = blockIdx.z * kLen;
    const int wr = wave >> 1, wc = wave & 1;

    f32x4 acc[4][4];
#pragma unroll
    for (int i = 0; i < 4; ++i)
#pragma unroll
        for (int j = 0; j < 4; ++j) acc[i][j] = (f32x4){0.f, 0.f, 0.f, 0.f};

    const int r_st = wave * 32 + (lane >> 3);
    const int s_st = ((lane & 7) ^ ((lane >> 4) & 3)) * 8;   // f16 units
    const _Float16* gA = A + (size_t)(bm + r_st) * K + kBase + s_st;
    const _Float16* gB = B + (size_t)(bn + r_st) * K + kBase + s_st;
    const size_t rstep8 = (size_t)8 * K;
    _Float16* lA = &lds[0][wave * 32][0];
    _Float16* lB = &lds[1][wave * 32][0];

    const int li = lane & 15;
    const int hi = lane >> 4;            // 0..3
    const int swb = (li >> 1) & 3;       // row-pair xor term

    for (int kt = 0; kt < kLen; kt += 64) {
#pragma unroll
        for (int ck = 0; ck < 4; ++ck) {
            gload16(gA + kt + ck * rstep8, lA + ck * 512);
            gload16(gB + kt + ck * rstep8, lB + ck * 512);
        }
        __syncthreads();

#pragma unroll
        for (int kk = 0; kk < 2; ++kk) {
            const int sw = (((kk << 2) | hi) ^ swb) * 8;     // f16 offset
            f16x8 a[4], b[4];
#pragma unroll
            for (int m = 0; m < 4; ++m)
                a[m] = *(const f16x8*)&lds[0][wr * 64 + m * 16 + li][sw];
#pragma unroll
            for (int n = 0; n < 4; ++n)
                b[n] = *(const f16x8*)&lds[1][wc * 64 + n * 16 + li][sw];
#pragma unroll
            for (int m = 0; m < 4; ++m)
#pragma unroll
                for (int n = 0; n < 4; ++n)
                    acc[m][n] = __builtin_amdgcn_mfma_f32_16x16x32_f16(a[m], b[n], acc[m][n], 0, 0, 0);
        }
        __syncthreads();
    }

    float* Pz = P + (size_t)blockIdx.z * M * N;
#pragma unroll
    for (int m = 0; m < 4; ++m)
#pragma unroll
        for (int n = 0; n < 4; ++n) {
            const int col = bn + wc * 64 + n * 16 + li;
#pragma unroll
            for (int e = 0; e < 4; ++e) {
                const int row = bm + wr * 64 + m * 16 + hi * 4 + e;
                Pz[(size_t)row * N + col] = acc[m][n][e];
            }
        }
}

// ---------------------------------------------------------------------------
// relu(sum_z P[z] + bias) -> f16
// ---------------------------------------------------------------------------
__global__ __launch_bounds__(256) void combine_relu_f16(
    const float* __restrict__ P, int Z, const float* __restrict__ bias,
    _Float16* __restrict__ H)
{
    const int g = blockIdx.x * 256 + threadIdx.x;
    const size_t MN4 = (size_t)NROI * HID / 4;
    float4 s = ((const float4*)P)[g];
    for (int z = 1; z < Z; ++z) {
        const float4 p = ((const float4*)P)[z * MN4 + g];
        s.x += p.x; s.y += p.y; s.z += p.z; s.w += p.w;
    }
    const float4 bv = *(const float4*)(bias + (g & 255) * 4);
    f16x4 o = {(_Float16)fmaxf(s.x + bv.x, 0.0f),
               (_Float16)fmaxf(s.y + bv.y, 0.0f),
               (_Float16)fmaxf(s.z + bv.z, 0.0f),
               (_Float16)fmaxf(s.w + bv.w, 0.0f)};
    ((f16x4*)H)[g] = o;
}

// ---------------------------------------------------------------------------
// relu(sum_z P[z] + bias) -> f32 (aliases P[0] elementwise - safe)
// ---------------------------------------------------------------------------
__global__ __launch_bounds__(256) void combine_relu_f32(
    const float* __restrict__ P, int Z, const float* __restrict__ bias,
    float* __restrict__ H)
{
    const int g = blockIdx.x * 256 + threadIdx.x;
    const size_t MN4 = (size_t)NROI * HID / 4;
    float4 s = ((const float4*)P)[g];
    for (int z = 1; z < Z; ++z) {
        const float4 p = ((const float4*)P)[z * MN4 + g];
        s.x += p.x; s.y += p.y; s.z += p.z; s.w += p.w;
    }
    const float4 bv = *(const float4*)(bias + (g & 255) * 4);
    float4 r;
    r.x = fmaxf(s.x + bv.x, 0.0f);
    r.y = fmaxf(s.y + bv.y, 0.0f);
    r.z = fmaxf(s.z + bv.z, 0.0f);
    r.w = fmaxf(s.w + bv.w, 0.0f);
    ((float4*)H)[g] = r;
}

// ---------------------------------------------------------------------------
// heads: one wave per ROI row; 10 dots of K=1024, shfl_xor reduce.
// ---------------------------------------------------------------------------
__global__ __launch_bounds__(256) void heads_kernel(
    const float* __restrict__ h2,
    const float* __restrict__ wc, const float* __restrict__ bc,
    const float* __restrict__ wb, const float* __restrict__ bb,
    float* __restrict__ out)
{
    const int gw   = (blockIdx.x * 256 + threadIdx.x) >> 6;
    const int lane = threadIdx.x & 63;
    const float* hrow = h2 + (size_t)gw * HID;

    float4 h[4];
#pragma unroll
    for (int j = 0; j < 4; ++j)
        h[j] = *(const float4*)(hrow + lane * 16 + j * 4);

    float keep = 0.0f;
#pragma unroll
    for (int o = 0; o < 10; ++o) {
        const float* wrow = (o < 2) ? (wc + (size_t)o * HID)
                                    : (wb + (size_t)(o - 2) * HID);
        float acc = 0.0f;
#pragma unroll
        for (int j = 0; j < 4; ++j) {
            const float4 w4 = *(const float4*)(wrow + lane * 16 + j * 4);
            acc += h[j].x * w4.x + h[j].y * w4.y + h[j].z * w4.z + h[j].w * w4.w;
        }
#pragma unroll
        for (int s = 32; s; s >>= 1) acc += __shfl_xor(acc, s, 64);
        if (lane == o) keep = acc;
    }
    if (lane < 2)        out[gw * 2 + lane] = keep + bc[lane];
    else if (lane < 10)  out[NROI * 2 + gw * 8 + (lane - 2)] = keep + bb[lane - 2];
}

// ---------------------------------------------------------------------------
extern "C" void kernel_launch(void* const* d_in, const int* in_sizes, int n_in,
                              void* d_out, int out_size, void* d_ws, size_t ws_size,
                              hipStream_t stream)
{
    const float* x    = (const float*)d_in[0];
    const float* rois = (const float*)d_in[1];
    const float* w1   = (const float*)d_in[2];
    const float* b1   = (const float*)d_in[3];
    const float* w2   = (const float*)d_in[4];
    const float* b2   = (const float*)d_in[5];
    const float* wc   = (const float*)d_in[6];
    const float* bc   = (const float*)d_in[7];
    const float* wb   = (const float*)d_in[8];
    const float* bb   = (const float*)d_in[9];
    float* out = (float*)d_out;

    char* ws = (char*)d_ws;
    const size_t CRB = (size_t)NROI * FANIN * 2;       // 51,380,224
    const size_t W1B = (size_t)HID * FANIN * 2;        // 25,690,112
    const size_t W2B = (size_t)HID * HID * 2;          //  2,097,152
    const size_t PB  = (size_t)NROI * HID * 4;         //  8,388,608 per z-slice
    const size_t HB  = (size_t)NROI * HID * 2;         //  4,194,304
    const size_t XTB = (size_t)4 * IMH * IMW * CCH * 2;// 81,920,000

    const int Z1 = 7;   // FC1 K-split: 12544/7 = 1792 = 28 x 64
    const int Z2 = 4;   // FC2 K-split: 1024/4  = 256 =  4 x 64

    size_t off = 0;
    _Float16* cropsP = (_Float16*)(ws + off); off += CRB;
    _Float16* w1P    = (_Float16*)(ws + off); off += W1B;
    _Float16* w2F    = (_Float16*)(ws + off); off += W2B;
    float*    P      = (float*)(ws + off);    off += (size_t)Z1 * PB;
    _Float16* h1F    = (_Float16*)(ws + off); off += HB;
    _Float16* xT     = (_Float16*)(ws + off); off += XTB;   // total ~224 MB
    float*    h2     = P;   // elementwise alias with P[0] in combine_relu_f32

    // weight prep
    permute_w1_kernel<<<HID, 256, 0, stream>>>(w1, w1P);
    convert_f16<<<1024, 256, 0, stream>>>(w2, w2F, HID * HID / 4);

    // x -> xT (f16, channel-last)
    transpose_f16<<<dim3(2, IMH, 4), 256, 0, stream>>>(x, xT);

    // RoIAlign gather: block per ROI, wave per sample
    roi_gather_kernel<<<NROI, 256, 0, stream>>>(xT, rois, cropsP);

    // FC1: K = 12544 (K-order p*256+c on both operands), 256x256 tile
    gemm_f16_256<<<dim3(HID / 256, NROI / 256, Z1), 512, 0, stream>>>(
        cropsP, w1P, P, NROI, HID, FANIN, FANIN / Z1);
    combine_relu_f16<<<(NROI * HID / 4) / 256, 256, 0, stream>>>(P, Z1, b1, h1F);

    // FC2: K = 1024, 128x128 tile
    gemm_f16<<<dim3(HID / 128, NROI / 128, Z2), 256, 0, stream>>>(
        h1F, w2F, P, NROI, HID, HID, HID / Z2);
    combine_relu_f32<<<(NROI * HID / 4) / 256, 256, 0, stream>>>(P, Z2, b2, h2);

    // heads
    heads_kernel<<<NROI / 4, 256, 0, stream>>>(h2, wc, bc, wb, bb, out);
}

// Round 17
// 217.446 us; speedup vs baseline: 1.2520x; 1.1111x over previous
//
#include <hip/hip_runtime.h>

#define NROI  2048
#define CCH   256
#define IMH   200
#define IMW   200
#define CROP  7
#define PP    49
#define FANIN 12544
#define HID   1024

typedef _Float16 f16x8 __attribute__((ext_vector_type(8)));
typedef _Float16 f16x4 __attribute__((ext_vector_type(4)));
typedef __attribute__((ext_vector_type(4))) float f32x4;

__device__ __forceinline__ void gload16(const void* g, void* l) {
    __builtin_amdgcn_global_load_lds(
        (const __attribute__((address_space(1))) void*)g,
        (__attribute__((address_space(3))) void*)l, 16, 0, 0);
}

// ---------------------------------------------------------------------------
// Transpose+convert: x[b][c][h][w] f32 -> xT[b][h][w][c] f16.
// ---------------------------------------------------------------------------
__global__ __launch_bounds__(256) void transpose_f16(
    const float* __restrict__ x, _Float16* __restrict__ xT)
{
    __shared__ _Float16 t[100][258];   // 51,600 B -> 3 blocks/CU

    const int half = blockIdx.x;       // 0,1
    const int h    = blockIdx.y;       // 0..199
    const int b    = blockIdx.z;       // 0..3
    const int c    = threadIdx.x;      // 0..255

    const float* src = x + ((size_t)(b * CCH + c) * IMH + h) * IMW + half * 100;
#pragma unroll
    for (int i = 0; i < 25; ++i) {
        const float4 v = *(const float4*)(src + i * 4);
        t[i * 4 + 0][c] = (_Float16)v.x;
        t[i * 4 + 1][c] = (_Float16)v.y;
        t[i * 4 + 2][c] = (_Float16)v.z;
        t[i * 4 + 3][c] = (_Float16)v.w;
    }
    __syncthreads();

    _Float16* dst = xT + ((size_t)(b * IMH + h) * IMW + half * 100) * CCH;
    const int wq = threadIdx.x >> 5;          // 0..7
    const int l32 = threadIdx.x & 31;
#pragma unroll
    for (int r = 0; r < 13; ++r) {
        const int w = r * 8 + wq;
        if (w < 100)
            *(f16x8*)(dst + (size_t)w * CCH + l32 * 8) =
                *(const f16x8*)&t[w][l32 * 8];
    }
}

// ---------------------------------------------------------------------------
// RoIAlign gather: block = ROI n, 4 waves; wave = one sample across channels.
// Crops K-order: k' = p*256 + c  (w1 permuted identically).
// ---------------------------------------------------------------------------
__global__ __launch_bounds__(256) void roi_gather_kernel(
    const _Float16* __restrict__ xT, const float* __restrict__ rois,
    _Float16* __restrict__ crops)
{
    const int n    = blockIdx.x;
    const int wave = threadIdx.x >> 6;
    const int lane = threadIdx.x & 63;

    const int   b   = (int)rois[(size_t)n * 5 + 0];
    const float rx1 = rois[(size_t)n * 5 + 1];
    const float ry1 = rois[(size_t)n * 5 + 2];
    const float rx2 = rois[(size_t)n * 5 + 3];
    const float ry2 = rois[(size_t)n * 5 + 4];
    const float bw = (rx2 - rx1) / 7.0f;
    const float bh = (ry2 - ry1) / 7.0f;

    const _Float16* xb = xT + (size_t)b * (IMH * IMW * CCH);
    _Float16* crow = crops + (size_t)n * FANIN;

    for (int p = wave; p < PP; p += 4) {
        const int i = p / 7;           // bin row -> y
        const int j = p - i * 7;       // bin col -> x
        float px = __fadd_rn(rx1, __fmul_rn((float)j + 0.5f, bw));
        float py = __fadd_rn(ry1, __fmul_rn((float)i + 0.5f, bh));
        px = fminf(fmaxf(px, 0.0f), (float)(IMW - 1));
        py = fminf(fmaxf(py, 0.0f), (float)(IMH - 1));
        const float fx = floorf(px), fy = floorf(py);
        const int x0 = (int)fx, y0 = (int)fy;
        const int dxo = (min(x0 + 1, IMW - 1) - x0) * CCH;
        const int dyo = (min(y0 + 1, IMH - 1) - y0) * (IMW * CCH);
        const float wx = px - fx, wy = py - fy;

        const _Float16* cb = xb + (size_t)(y0 * IMW + x0) * CCH + lane * 4;
        const f16x4 A = *(const f16x4*)(cb);
        const f16x4 B = *(const f16x4*)(cb + dxo);
        const f16x4 C = *(const f16x4*)(cb + dyo);
        const f16x4 D = *(const f16x4*)(cb + dyo + dxo);

        f16x4 o;
#pragma unroll
        for (int e = 0; e < 4; ++e) {
            const float v00 = (float)A[e], v01 = (float)B[e];
            const float v10 = (float)C[e], v11 = (float)D[e];
            const float top = v00 + wx * (v01 - v00);
            const float bot = v10 + wx * (v11 - v10);
            o[e] = (_Float16)(top + wy * (bot - top));
        }
        *(f16x4*)(crow + p * CCH + lane * 4) = o;
    }
}

// ---------------------------------------------------------------------------
// w1 permute+convert: w1P[o][p*256+c] = (f16) w1[o][c*49+p].
// ---------------------------------------------------------------------------
__global__ __launch_bounds__(256) void permute_w1_kernel(
    const float* __restrict__ w1, _Float16* __restrict__ w1P)
{
    __shared__ _Float16 row[FANIN];    // 25,088 B

    const int o   = blockIdx.x;
    const int tid = threadIdx.x;
    const float* src = w1 + (size_t)o * FANIN;

    for (int g = tid; g < FANIN / 4; g += 256) {
        const float4 v = *(const float4*)(src + g * 4);
        f16x4 f = {(_Float16)v.x, (_Float16)v.y, (_Float16)v.z, (_Float16)v.w};
        *(f16x4*)&row[g * 4] = f;
    }
    __syncthreads();

    _Float16* dst = w1P + (size_t)o * FANIN;
    for (int g = tid; g < FANIN; g += 256) {
        const int p = g >> 8;          // 0..48
        const int c = g & 255;
        dst[g] = row[c * PP + p];
    }
}

// ---------------------------------------------------------------------------
// f32 -> f16 conversion (w2), vectorized.
// ---------------------------------------------------------------------------
__global__ __launch_bounds__(256) void convert_f16(
    const float* __restrict__ w, _Float16* __restrict__ wF, int n4)
{
    for (int g = blockIdx.x * 256 + threadIdx.x; g < n4; g += gridDim.x * 256) {
        const float4 v = ((const float4*)w)[g];
        f16x4 o = {(_Float16)v.x, (_Float16)v.y, (_Float16)v.z, (_Float16)v.w};
        ((f16x4*)wF)[g] = o;
    }
}

// ---------------------------------------------------------------------------
// FC1 GEMM (NT), 256x256 tile, BK=64, 8 waves, DOUBLE-BUFFERED 2-phase:
// STAGE(buf^1, t+1) issued BEFORE compute(buf) -> stage latency hides under
// the 512-MFMA phase; single barrier per K-step (drains prefetch + protects
// buffer reuse). Verified XOR swizzle: LDS[row][s] = global slot
// s ^ ((row>>1)&3); read slot (kk*4+hi) ^ ((li>>1)&3).
// ---------------------------------------------------------------------------
__global__ __launch_bounds__(512, 1) void gemm_f16_256(
    const _Float16* __restrict__ A, const _Float16* __restrict__ B,
    float* __restrict__ P, int M, int N, int K, int kLen)
{
    __shared__ _Float16 lds[2][2][256][64];   // [buf][op][row][slot] 128 KB

    const int tid  = threadIdx.x;
    const int wave = tid >> 6;           // 0..7
    const int lane = tid & 63;
    const int bm = blockIdx.y * 256;
    const int bn = blockIdx.x * 256;
    const int kBase = blockIdx.z * kLen;
    const int wr = wave >> 1;            // 0..3 (M)
    const int wc = wave & 1;             // 0..1 (N)

    f32x4 acc[4][8];
#pragma unroll
    for (int i = 0; i < 4; ++i)
#pragma unroll
        for (int j = 0; j < 8; ++j) acc[i][j] = (f32x4){0.f, 0.f, 0.f, 0.f};

    const int r_st = wave * 32 + (lane >> 3);
    const int s_st = ((lane & 7) ^ ((lane >> 4) & 3)) * 8;   // f16 units
    const _Float16* gA = A + (size_t)(bm + r_st) * K + kBase + s_st;
    const _Float16* gB = B + (size_t)(bn + r_st) * K + kBase + s_st;
    const size_t rstep8 = (size_t)8 * K;

    const int li = lane & 15;
    const int hi = lane >> 4;            // 0..3
    const int swb = (li >> 1) & 3;       // row-pair xor term

    // prologue: stage tile 0 into buf 0
    {
        _Float16* dA = &lds[0][0][wave * 32][0];
        _Float16* dB = &lds[0][1][wave * 32][0];
#pragma unroll
        for (int ck = 0; ck < 4; ++ck) {
            gload16(gA + ck * rstep8, dA + ck * 512);
            gload16(gB + ck * rstep8, dB + ck * 512);
        }
    }
    __syncthreads();

    int cur = 0;
    for (int kt = 0; kt < kLen; kt += 64) {
        // issue next tile's stage into buf^1 (flies under the MFMA phase)
        if (kt + 64 < kLen) {
            _Float16* dA = &lds[cur ^ 1][0][wave * 32][0];
            _Float16* dB = &lds[cur ^ 1][1][wave * 32][0];
#pragma unroll
            for (int ck = 0; ck < 4; ++ck) {
                gload16(gA + kt + 64 + ck * rstep8, dA + ck * 512);
                gload16(gB + kt + 64 + ck * rstep8, dB + ck * 512);
            }
        }

        // compute from buf cur
#pragma unroll
        for (int kk = 0; kk < 2; ++kk) {
            const int sw = (((kk << 2) | hi) ^ swb) * 8;     // f16 offset
            f16x8 a[4], b[8];
#pragma unroll
            for (int m = 0; m < 4; ++m)
                a[m] = *(const f16x8*)&lds[cur][0][wr * 64 + m * 16 + li][sw];
#pragma unroll
            for (int n = 0; n < 8; ++n)
                b[n] = *(const f16x8*)&lds[cur][1][wc * 128 + n * 16 + li][sw];
#pragma unroll
            for (int m = 0; m < 4; ++m)
#pragma unroll
                for (int n = 0; n < 8; ++n)
                    acc[m][n] = __builtin_amdgcn_mfma_f32_16x16x32_f16(a[m], b[n], acc[m][n], 0, 0, 0);
        }
        __syncthreads();   // drains prefetch (vmcnt) + LDS reads (lgkmcnt)
        cur ^= 1;
    }

    float* Pz = P + (size_t)blockIdx.z * M * N;
#pragma unroll
    for (int m = 0; m < 4; ++m)
#pragma unroll
        for (int n = 0; n < 8; ++n) {
            const int col = bn + wc * 128 + n * 16 + li;
#pragma unroll
            for (int e = 0; e < 4; ++e) {
                const int row = bm + wr * 64 + m * 16 + hi * 4 + e;
                Pz[(size_t)row * N + col] = acc[m][n][e];
            }
        }
}

// ---------------------------------------------------------------------------
// FC2 GEMM (NT), 128x128 tile, BK=64, double-buffered 2-phase (as above).
// ---------------------------------------------------------------------------
__global__ __launch_bounds__(256, 2) void gemm_f16(
    const _Float16* __restrict__ A, const _Float16* __restrict__ B,
    float* __restrict__ P, int M, int N, int K, int kLen)
{
    __shared__ _Float16 lds[2][2][128][64];   // 64 KB -> 2 blocks/CU

    const int tid  = threadIdx.x;
    const int wave = tid >> 6;
    const int lane = tid & 63;
    const int bm = blockIdx.y * 128;
    const int bn = blockIdx.x * 128;
    const int kBase = blockIdx.z * kLen;
    const int wr = wave >> 1, wc = wave & 1;

    f32x4 acc[4][4];
#pragma unroll
    for (int i = 0; i < 4; ++i)
#pragma unroll
        for (int j = 0; j < 4; ++j) acc[i][j] = (f32x4){0.f, 0.f, 0.f, 0.f};

    const int r_st = wave * 32 + (lane >> 3);
    const int s_st = ((lane & 7) ^ ((lane >> 4) & 3)) * 8;   // f16 units
    const _Float16* gA = A + (size_t)(bm + r_st) * K + kBase + s_st;
    const _Float16* gB = B + (size_t)(bn + r_st) * K + kBase + s_st;
    const size_t rstep8 = (size_t)8 * K;

    const int li = lane & 15;
    const int hi = lane >> 4;            // 0..3
    const int swb = (li >> 1) & 3;       // row-pair xor term

    {
        _Float16* dA = &lds[0][0][wave * 32][0];
        _Float16* dB = &lds[0][1][wave * 32][0];
#pragma unroll
        for (int ck = 0; ck < 4; ++ck) {
            gload16(gA + ck * rstep8, dA + ck * 512);
            gload16(gB + ck * rstep8, dB + ck * 512);
        }
    }
    __syncthreads();

    int cur = 0;
    for (int kt = 0; kt < kLen; kt += 64) {
        if (kt + 64 < kLen) {
            _Float16* dA = &lds[cur ^ 1][0][wave * 32][0];
            _Float16* dB = &lds[cur ^ 1][1][wave * 32][0];
#pragma unroll
            for (int ck = 0; ck < 4; ++ck) {
                gload16(gA + kt + 64 + ck * rstep8, dA + ck * 512);
                gload16(gB + kt + 64 + ck * rstep8, dB + ck * 512);
            }
        }

#pragma unroll
        for (int kk = 0; kk < 2; ++kk) {
            const int sw = (((kk << 2) | hi) ^ swb) * 8;     // f16 offset
            f16x8 a[4], b[4];
#pragma unroll
            for (int m = 0; m < 4; ++m)
                a[m] = *(const f16x8*)&lds[cur][0][wr * 64 + m * 16 + li][sw];
#pragma unroll
            for (int n = 0; n < 4; ++n)
                b[n] = *(const f16x8*)&lds[cur][1][wc * 64 + n * 16 + li][sw];
#pragma unroll
            for (int m = 0; m < 4; ++m)
#pragma unroll
                for (int n = 0; n < 4; ++n)
                    acc[m][n] = __builtin_amdgcn_mfma_f32_16x16x32_f16(a[m], b[n], acc[m][n], 0, 0, 0);
        }
        __syncthreads();
        cur ^= 1;
    }

    float* Pz = P + (size_t)blockIdx.z * M * N;
#pragma unroll
    for (int m = 0; m < 4; ++m)
#pragma unroll
        for (int n = 0; n < 4; ++n) {
            const int col = bn + wc * 64 + n * 16 + li;
#pragma unroll
            for (int e = 0; e < 4; ++e) {
                const int row = bm + wr * 64 + m * 16 + hi * 4 + e;
                Pz[(size_t)row * N + col] = acc[m][n][e];
            }
        }
}

// ---------------------------------------------------------------------------
// relu(sum_z P[z] + bias) -> f16
// ---------------------------------------------------------------------------
__global__ __launch_bounds__(256) void combine_relu_f16(
    const float* __restrict__ P, int Z, const float* __restrict__ bias,
    _Float16* __restrict__ H)
{
    const int g = blockIdx.x * 256 + threadIdx.x;
    const size_t MN4 = (size_t)NROI * HID / 4;
    float4 s = ((const float4*)P)[g];
    for (int z = 1; z < Z; ++z) {
        const float4 p = ((const float4*)P)[z * MN4 + g];
        s.x += p.x; s.y += p.y; s.z += p.z; s.w += p.w;
    }
    const float4 bv = *(const float4*)(bias + (g & 255) * 4);
    f16x4 o = {(_Float16)fmaxf(s.x + bv.x, 0.0f),
               (_Float16)fmaxf(s.y + bv.y, 0.0f),
               (_Float16)fmaxf(s.z + bv.z, 0.0f),
               (_Float16)fmaxf(s.w + bv.w, 0.0f)};
    ((f16x4*)H)[g] = o;
}

// ---------------------------------------------------------------------------
// relu(sum_z P[z] + bias) -> f32 (aliases P[0] elementwise - safe)
// ---------------------------------------------------------------------------
__global__ __launch_bounds__(256) void combine_relu_f32(
    const float* __restrict__ P, int Z, const float* __restrict__ bias,
    float* __restrict__ H)
{
    const int g = blockIdx.x * 256 + threadIdx.x;
    const size_t MN4 = (size_t)NROI * HID / 4;
    float4 s = ((const float4*)P)[g];
    for (int z = 1; z < Z; ++z) {
        const float4 p = ((const float4*)P)[z * MN4 + g];
        s.x += p.x; s.y += p.y; s.z += p.z; s.w += p.w;
    }
    const float4 bv = *(const float4*)(bias + (g & 255) * 4);
    float4 r;
    r.x = fmaxf(s.x + bv.x, 0.0f);
    r.y = fmaxf(s.y + bv.y, 0.0f);
    r.z = fmaxf(s.z + bv.z, 0.0f);
    r.w = fmaxf(s.w + bv.w, 0.0f);
    ((float4*)H)[g] = r;
}

// ---------------------------------------------------------------------------
// heads: one wave per ROI row; 10 dots of K=1024, shfl_xor reduce.
// ---------------------------------------------------------------------------
__global__ __launch_bounds__(256) void heads_kernel(
    const float* __restrict__ h2,
    const float* __restrict__ wc, const float* __restrict__ bc,
    const float* __restrict__ wb, const float* __restrict__ bb,
    float* __restrict__ out)
{
    const int gw   = (blockIdx.x * 256 + threadIdx.x) >> 6;
    const int lane = threadIdx.x & 63;
    const float* hrow = h2 + (size_t)gw * HID;

    float4 h[4];
#pragma unroll
    for (int j = 0; j < 4; ++j)
        h[j] = *(const float4*)(hrow + lane * 16 + j * 4);

    float keep = 0.0f;
#pragma unroll
    for (int o = 0; o < 10; ++o) {
        const float* wrow = (o < 2) ? (wc + (size_t)o * HID)
                                    : (wb + (size_t)(o - 2) * HID);
        float acc = 0.0f;
#pragma unroll
        for (int j = 0; j < 4; ++j) {
            const float4 w4 = *(const float4*)(wrow + lane * 16 + j * 4);
            acc += h[j].x * w4.x + h[j].y * w4.y + h[j].z * w4.z + h[j].w * w4.w;
        }
#pragma unroll
        for (int s = 32; s; s >>= 1) acc += __shfl_xor(acc, s, 64);
        if (lane == o) keep = acc;
    }
    if (lane < 2)        out[gw * 2 + lane] = keep + bc[lane];
    else if (lane < 10)  out[NROI * 2 + gw * 8 + (lane - 2)] = keep + bb[lane - 2];
}

// ---------------------------------------------------------------------------
extern "C" void kernel_launch(void* const* d_in, const int* in_sizes, int n_in,
                              void* d_out, int out_size, void* d_ws, size_t ws_size,
                              hipStream_t stream)
{
    const float* x    = (const float*)d_in[0];
    const float* rois = (const float*)d_in[1];
    const float* w1   = (const float*)d_in[2];
    const float* b1   = (const float*)d_in[3];
    const float* w2   = (const float*)d_in[4];
    const float* b2   = (const float*)d_in[5];
    const float* wc   = (const float*)d_in[6];
    const float* bc   = (const float*)d_in[7];
    const float* wb   = (const float*)d_in[8];
    const float* bb   = (const float*)d_in[9];
    float* out = (float*)d_out;

    char* ws = (char*)d_ws;
    const size_t CRB = (size_t)NROI * FANIN * 2;       // 51,380,224
    const size_t W1B = (size_t)HID * FANIN * 2;        // 25,690,112
    const size_t W2B = (size_t)HID * HID * 2;          //  2,097,152
    const size_t PB  = (size_t)NROI * HID * 4;         //  8,388,608 per z-slice
    const size_t HB  = (size_t)NROI * HID * 2;         //  4,194,304
    const size_t XTB = (size_t)4 * IMH * IMW * CCH * 2;// 81,920,000

    const int Z1 = 7;   // FC1 K-split: 12544/7 = 1792 = 28 x 64
    const int Z2 = 4;   // FC2 K-split: 1024/4  = 256 =  4 x 64

    size_t off = 0;
    _Float16* cropsP = (_Float16*)(ws + off); off += CRB;
    _Float16* w1P    = (_Float16*)(ws + off); off += W1B;
    _Float16* w2F    = (_Float16*)(ws + off); off += W2B;
    float*    P      = (float*)(ws + off);    off += (size_t)Z1 * PB;
    _Float16* h1F    = (_Float16*)(ws + off); off += HB;
    _Float16* xT     = (_Float16*)(ws + off); off += XTB;   // total ~224 MB
    float*    h2     = P;   // elementwise alias with P[0] in combine_relu_f32

    // weight prep
    permute_w1_kernel<<<HID, 256, 0, stream>>>(w1, w1P);
    convert_f16<<<1024, 256, 0, stream>>>(w2, w2F, HID * HID / 4);

    // x -> xT (f16, channel-last)
    transpose_f16<<<dim3(2, IMH, 4), 256, 0, stream>>>(x, xT);

    // RoIAlign gather: block per ROI, wave per sample
    roi_gather_kernel<<<NROI, 256, 0, stream>>>(xT, rois, cropsP);

    // FC1: K = 12544 (K-order p*256+c on both operands), 256x256 dbuf tile
    gemm_f16_256<<<dim3(HID / 256, NROI / 256, Z1), 512, 0, stream>>>(
        cropsP, w1P, P, NROI, HID, FANIN, FANIN / Z1);
    combine_relu_f16<<<(NROI * HID / 4) / 256, 256, 0, stream>>>(P, Z1, b1, h1F);

    // FC2: K = 1024, 128x128 dbuf tile
    gemm_f16<<<dim3(HID / 128, NROI / 128, Z2), 256, 0, stream>>>(
        h1F, w2F, P, NROI, HID, HID, HID / Z2);
    combine_relu_f32<<<(NROI * HID / 4) / 256, 256, 0, stream>>>(P, Z2, b2, h2);

    // heads
    heads_kernel<<<NROI / 4, 256, 0, stream>>>(h2, wc, bc, wb, bb, out);
}

// Round 18
// 216.692 us; speedup vs baseline: 1.2563x; 1.0035x over previous
//
#include <hip/hip_runtime.h>

#define NROI  2048
#define CCH   256
#define IMH   200
#define IMW   200
#define CROP  7
#define PP    49
#define FANIN 12544
#define HID   1024

typedef _Float16 f16x8 __attribute__((ext_vector_type(8)));
typedef _Float16 f16x4 __attribute__((ext_vector_type(4)));
typedef __attribute__((ext_vector_type(4))) float f32x4;

__device__ __forceinline__ void gload16(const void* g, void* l) {
    __builtin_amdgcn_global_load_lds(
        (const __attribute__((address_space(1))) void*)g,
        (__attribute__((address_space(3))) void*)l, 16, 0, 0);
}

// ---------------------------------------------------------------------------
// Transpose+convert: x[b][c][h][w] f32 -> xT[b][h][w][c] f16.
// ---------------------------------------------------------------------------
__global__ __launch_bounds__(256) void transpose_f16(
    const float* __restrict__ x, _Float16* __restrict__ xT)
{
    __shared__ _Float16 t[100][258];   // 51,600 B -> 3 blocks/CU

    const int half = blockIdx.x;       // 0,1
    const int h    = blockIdx.y;       // 0..199
    const int b    = blockIdx.z;       // 0..3
    const int c    = threadIdx.x;      // 0..255

    const float* src = x + ((size_t)(b * CCH + c) * IMH + h) * IMW + half * 100;
#pragma unroll
    for (int i = 0; i < 25; ++i) {
        const float4 v = *(const float4*)(src + i * 4);
        t[i * 4 + 0][c] = (_Float16)v.x;
        t[i * 4 + 1][c] = (_Float16)v.y;
        t[i * 4 + 2][c] = (_Float16)v.z;
        t[i * 4 + 3][c] = (_Float16)v.w;
    }
    __syncthreads();

    _Float16* dst = xT + ((size_t)(b * IMH + h) * IMW + half * 100) * CCH;
    const int wq = threadIdx.x >> 5;          // 0..7
    const int l32 = threadIdx.x & 31;
#pragma unroll
    for (int r = 0; r < 13; ++r) {
        const int w = r * 8 + wq;
        if (w < 100)
            *(f16x8*)(dst + (size_t)w * CCH + l32 * 8) =
                *(const f16x8*)&t[w][l32 * 8];
    }
}

// ---------------------------------------------------------------------------
// RoIAlign gather: block = ROI n, 4 waves; wave = one sample across channels.
// Crops K-order: k' = p*256 + c  (w1 permuted identically).
// ---------------------------------------------------------------------------
__global__ __launch_bounds__(256) void roi_gather_kernel(
    const _Float16* __restrict__ xT, const float* __restrict__ rois,
    _Float16* __restrict__ crops)
{
    const int n    = blockIdx.x;
    const int wave = threadIdx.x >> 6;
    const int lane = threadIdx.x & 63;

    const int   b   = (int)rois[(size_t)n * 5 + 0];
    const float rx1 = rois[(size_t)n * 5 + 1];
    const float ry1 = rois[(size_t)n * 5 + 2];
    const float rx2 = rois[(size_t)n * 5 + 3];
    const float ry2 = rois[(size_t)n * 5 + 4];
    const float bw = (rx2 - rx1) / 7.0f;
    const float bh = (ry2 - ry1) / 7.0f;

    const _Float16* xb = xT + (size_t)b * (IMH * IMW * CCH);
    _Float16* crow = crops + (size_t)n * FANIN;

    for (int p = wave; p < PP; p += 4) {
        const int i = p / 7;           // bin row -> y
        const int j = p - i * 7;       // bin col -> x
        float px = __fadd_rn(rx1, __fmul_rn((float)j + 0.5f, bw));
        float py = __fadd_rn(ry1, __fmul_rn((float)i + 0.5f, bh));
        px = fminf(fmaxf(px, 0.0f), (float)(IMW - 1));
        py = fminf(fmaxf(py, 0.0f), (float)(IMH - 1));
        const float fx = floorf(px), fy = floorf(py);
        const int x0 = (int)fx, y0 = (int)fy;
        const int dxo = (min(x0 + 1, IMW - 1) - x0) * CCH;
        const int dyo = (min(y0 + 1, IMH - 1) - y0) * (IMW * CCH);
        const float wx = px - fx, wy = py - fy;

        const _Float16* cb = xb + (size_t)(y0 * IMW + x0) * CCH + lane * 4;
        const f16x4 A = *(const f16x4*)(cb);
        const f16x4 B = *(const f16x4*)(cb + dxo);
        const f16x4 C = *(const f16x4*)(cb + dyo);
        const f16x4 D = *(const f16x4*)(cb + dyo + dxo);

        f16x4 o;
#pragma unroll
        for (int e = 0; e < 4; ++e) {
            const float v00 = (float)A[e], v01 = (float)B[e];
            const float v10 = (float)C[e], v11 = (float)D[e];
            const float top = v00 + wx * (v01 - v00);
            const float bot = v10 + wx * (v11 - v10);
            o[e] = (_Float16)(top + wy * (bot - top));
        }
        *(f16x4*)(crow + p * CCH + lane * 4) = o;
    }
}

// ---------------------------------------------------------------------------
// w1 permute+convert: w1P[o][p*256+c] = (f16) w1[o][c*49+p].
// ---------------------------------------------------------------------------
__global__ __launch_bounds__(256) void permute_w1_kernel(
    const float* __restrict__ w1, _Float16* __restrict__ w1P)
{
    __shared__ _Float16 row[FANIN];    // 25,088 B

    const int o   = blockIdx.x;
    const int tid = threadIdx.x;
    const float* src = w1 + (size_t)o * FANIN;

    for (int g = tid; g < FANIN / 4; g += 256) {
        const float4 v = *(const float4*)(src + g * 4);
        f16x4 f = {(_Float16)v.x, (_Float16)v.y, (_Float16)v.z, (_Float16)v.w};
        *(f16x4*)&row[g * 4] = f;
    }
    __syncthreads();

    _Float16* dst = w1P + (size_t)o * FANIN;
    for (int g = tid; g < FANIN; g += 256) {
        const int p = g >> 8;          // 0..48
        const int c = g & 255;
        dst[g] = row[c * PP + p];
    }
}

// ---------------------------------------------------------------------------
// f32 -> f16 conversion (w2), vectorized.
// ---------------------------------------------------------------------------
__global__ __launch_bounds__(256) void convert_f16(
    const float* __restrict__ w, _Float16* __restrict__ wF, int n4)
{
    for (int g = blockIdx.x * 256 + threadIdx.x; g < n4; g += gridDim.x * 256) {
        const float4 v = ((const float4*)w)[g];
        f16x4 o = {(_Float16)v.x, (_Float16)v.y, (_Float16)v.z, (_Float16)v.w};
        ((f16x4*)wF)[g] = o;
    }
}

// ---------------------------------------------------------------------------
// FC1 GEMM (NT), 256x256 tile, BK=64, 8 waves, double-buffered 2-phase,
// XCD-pinned flat grid (224 blocks): xcd=flat&7 (default round-robin XCD
// assignment), bn=xcd&3, half=xcd>>2, bm=half*4+(idx&3), z=idx>>2.
// All blocks sharing a B-panel (bn,z) land on ONE XCD -> w1P served from
// that XCD's L2; B L3 traffic drops ~4x.
// ---------------------------------------------------------------------------
__global__ __launch_bounds__(512, 1) void gemm_f16_256(
    const _Float16* __restrict__ A, const _Float16* __restrict__ B,
    float* __restrict__ P, int M, int N, int K, int kLen)
{
    __shared__ _Float16 lds[2][2][256][64];   // [buf][op][row][slot] 128 KB

    const int flat = blockIdx.x;
    const int xcd  = flat & 7;
    const int idx  = flat >> 3;          // 0..27
    const int bn4  = xcd & 3;            // n-tile 0..3
    const int half = xcd >> 2;           // 0..1
    const int bm8  = half * 4 + (idx & 3);   // m-tile 0..7
    const int z    = idx >> 2;           // 0..6

    const int tid  = threadIdx.x;
    const int wave = tid >> 6;           // 0..7
    const int lane = tid & 63;
    const int bm = bm8 * 256;
    const int bn = bn4 * 256;
    const int kBase = z * kLen;
    const int wr = wave >> 1;            // 0..3 (M)
    const int wc = wave & 1;             // 0..1 (N)

    f32x4 acc[4][8];
#pragma unroll
    for (int i = 0; i < 4; ++i)
#pragma unroll
        for (int j = 0; j < 8; ++j) acc[i][j] = (f32x4){0.f, 0.f, 0.f, 0.f};

    const int r_st = wave * 32 + (lane >> 3);
    const int s_st = ((lane & 7) ^ ((lane >> 4) & 3)) * 8;   // f16 units
    const _Float16* gA = A + (size_t)(bm + r_st) * K + kBase + s_st;
    const _Float16* gB = B + (size_t)(bn + r_st) * K + kBase + s_st;
    const size_t rstep8 = (size_t)8 * K;

    const int li = lane & 15;
    const int hi = lane >> 4;            // 0..3
    const int swb = (li >> 1) & 3;       // row-pair xor term

    // prologue: stage tile 0 into buf 0
    {
        _Float16* dA = &lds[0][0][wave * 32][0];
        _Float16* dB = &lds[0][1][wave * 32][0];
#pragma unroll
        for (int ck = 0; ck < 4; ++ck) {
            gload16(gA + ck * rstep8, dA + ck * 512);
            gload16(gB + ck * rstep8, dB + ck * 512);
        }
    }
    __syncthreads();

    int cur = 0;
    for (int kt = 0; kt < kLen; kt += 64) {
        if (kt + 64 < kLen) {
            _Float16* dA = &lds[cur ^ 1][0][wave * 32][0];
            _Float16* dB = &lds[cur ^ 1][1][wave * 32][0];
#pragma unroll
            for (int ck = 0; ck < 4; ++ck) {
                gload16(gA + kt + 64 + ck * rstep8, dA + ck * 512);
                gload16(gB + kt + 64 + ck * rstep8, dB + ck * 512);
            }
        }

#pragma unroll
        for (int kk = 0; kk < 2; ++kk) {
            const int sw = (((kk << 2) | hi) ^ swb) * 8;     // f16 offset
            f16x8 a[4], b[8];
#pragma unroll
            for (int m = 0; m < 4; ++m)
                a[m] = *(const f16x8*)&lds[cur][0][wr * 64 + m * 16 + li][sw];
#pragma unroll
            for (int n = 0; n < 8; ++n)
                b[n] = *(const f16x8*)&lds[cur][1][wc * 128 + n * 16 + li][sw];
#pragma unroll
            for (int m = 0; m < 4; ++m)
#pragma unroll
                for (int n = 0; n < 8; ++n)
                    acc[m][n] = __builtin_amdgcn_mfma_f32_16x16x32_f16(a[m], b[n], acc[m][n], 0, 0, 0);
        }
        __syncthreads();
        cur ^= 1;
    }

    float* Pz = P + (size_t)z * M * N;
#pragma unroll
    for (int m = 0; m < 4; ++m)
#pragma unroll
        for (int n = 0; n < 8; ++n) {
            const int col = bn + wc * 128 + n * 16 + li;
#pragma unroll
            for (int e = 0; e < 4; ++e) {
                const int row = bm + wr * 64 + m * 16 + hi * 4 + e;
                Pz[(size_t)row * N + col] = acc[m][n][e];
            }
        }
}

// ---------------------------------------------------------------------------
// FC2 GEMM (NT), 128x128 tile, BK=64, double-buffered 2-phase.
// ---------------------------------------------------------------------------
__global__ __launch_bounds__(256, 2) void gemm_f16(
    const _Float16* __restrict__ A, const _Float16* __restrict__ B,
    float* __restrict__ P, int M, int N, int K, int kLen)
{
    __shared__ _Float16 lds[2][2][128][64];   // 64 KB -> 2 blocks/CU

    const int tid  = threadIdx.x;
    const int wave = tid >> 6;
    const int lane = tid & 63;
    const int bm = blockIdx.y * 128;
    const int bn = blockIdx.x * 128;
    const int kBase = blockIdx.z * kLen;
    const int wr = wave >> 1, wc = wave & 1;

    f32x4 acc[4][4];
#pragma unroll
    for (int i = 0; i < 4; ++i)
#pragma unroll
        for (int j = 0; j < 4; ++j) acc[i][j] = (f32x4){0.f, 0.f, 0.f, 0.f};

    const int r_st = wave * 32 + (lane >> 3);
    const int s_st = ((lane & 7) ^ ((lane >> 4) & 3)) * 8;   // f16 units
    const _Float16* gA = A + (size_t)(bm + r_st) * K + kBase + s_st;
    const _Float16* gB = B + (size_t)(bn + r_st) * K + kBase + s_st;
    const size_t rstep8 = (size_t)8 * K;

    const int li = lane & 15;
    const int hi = lane >> 4;            // 0..3
    const int swb = (li >> 1) & 3;       // row-pair xor term

    {
        _Float16* dA = &lds[0][0][wave * 32][0];
        _Float16* dB = &lds[0][1][wave * 32][0];
#pragma unroll
        for (int ck = 0; ck < 4; ++ck) {
            gload16(gA + ck * rstep8, dA + ck * 512);
            gload16(gB + ck * rstep8, dB + ck * 512);
        }
    }
    __syncthreads();

    int cur = 0;
    for (int kt = 0; kt < kLen; kt += 64) {
        if (kt + 64 < kLen) {
            _Float16* dA = &lds[cur ^ 1][0][wave * 32][0];
            _Float16* dB = &lds[cur ^ 1][1][wave * 32][0];
#pragma unroll
            for (int ck = 0; ck < 4; ++ck) {
                gload16(gA + kt + 64 + ck * rstep8, dA + ck * 512);
                gload16(gB + kt + 64 + ck * rstep8, dB + ck * 512);
            }
        }

#pragma unroll
        for (int kk = 0; kk < 2; ++kk) {
            const int sw = (((kk << 2) | hi) ^ swb) * 8;     // f16 offset
            f16x8 a[4], b[4];
#pragma unroll
            for (int m = 0; m < 4; ++m)
                a[m] = *(const f16x8*)&lds[cur][0][wr * 64 + m * 16 + li][sw];
#pragma unroll
            for (int n = 0; n < 4; ++n)
                b[n] = *(const f16x8*)&lds[cur][1][wc * 64 + n * 16 + li][sw];
#pragma unroll
            for (int m = 0; m < 4; ++m)
#pragma unroll
                for (int n = 0; n < 4; ++n)
                    acc[m][n] = __builtin_amdgcn_mfma_f32_16x16x32_f16(a[m], b[n], acc[m][n], 0, 0, 0);
        }
        __syncthreads();
        cur ^= 1;
    }

    float* Pz = P + (size_t)blockIdx.z * M * N;
#pragma unroll
    for (int m = 0; m < 4; ++m)
#pragma unroll
        for (int n = 0; n < 4; ++n) {
            const int col = bn + wc * 64 + n * 16 + li;
#pragma unroll
            for (int e = 0; e < 4; ++e) {
                const int row = bm + wr * 64 + m * 16 + hi * 4 + e;
                Pz[(size_t)row * N + col] = acc[m][n][e];
            }
        }
}

// ---------------------------------------------------------------------------
// relu(sum_z P[z] + bias) -> f16
// ---------------------------------------------------------------------------
__global__ __launch_bounds__(256) void combine_relu_f16(
    const float* __restrict__ P, int Z, const float* __restrict__ bias,
    _Float16* __restrict__ H)
{
    const int g = blockIdx.x * 256 + threadIdx.x;
    const size_t MN4 = (size_t)NROI * HID / 4;
    float4 s = ((const float4*)P)[g];
    for (int z = 1; z < Z; ++z) {
        const float4 p = ((const float4*)P)[z * MN4 + g];
        s.x += p.x; s.y += p.y; s.z += p.z; s.w += p.w;
    }
    const float4 bv = *(const float4*)(bias + (g & 255) * 4);
    f16x4 o = {(_Float16)fmaxf(s.x + bv.x, 0.0f),
               (_Float16)fmaxf(s.y + bv.y, 0.0f),
               (_Float16)fmaxf(s.z + bv.z, 0.0f),
               (_Float16)fmaxf(s.w + bv.w, 0.0f)};
    ((f16x4*)H)[g] = o;
}

// ---------------------------------------------------------------------------
// relu(sum_z P[z] + bias) -> f32 (aliases P[0] elementwise - safe)
// ---------------------------------------------------------------------------
__global__ __launch_bounds__(256) void combine_relu_f32(
    const float* __restrict__ P, int Z, const float* __restrict__ bias,
    float* __restrict__ H)
{
    const int g = blockIdx.x * 256 + threadIdx.x;
    const size_t MN4 = (size_t)NROI * HID / 4;
    float4 s = ((const float4*)P)[g];
    for (int z = 1; z < Z; ++z) {
        const float4 p = ((const float4*)P)[z * MN4 + g];
        s.x += p.x; s.y += p.y; s.z += p.z; s.w += p.w;
    }
    const float4 bv = *(const float4*)(bias + (g & 255) * 4);
    float4 r;
    r.x = fmaxf(s.x + bv.x, 0.0f);
    r.y = fmaxf(s.y + bv.y, 0.0f);
    r.z = fmaxf(s.z + bv.z, 0.0f);
    r.w = fmaxf(s.w + bv.w, 0.0f);
    ((float4*)H)[g] = r;
}

// ---------------------------------------------------------------------------
// heads: one wave per ROI row; 10 dots of K=1024, shfl_xor reduce.
// ---------------------------------------------------------------------------
__global__ __launch_bounds__(256) void heads_kernel(
    const float* __restrict__ h2,
    const float* __restrict__ wc, const float* __restrict__ bc,
    const float* __restrict__ wb, const float* __restrict__ bb,
    float* __restrict__ out)
{
    const int gw   = (blockIdx.x * 256 + threadIdx.x) >> 6;
    const int lane = threadIdx.x & 63;
    const float* hrow = h2 + (size_t)gw * HID;

    float4 h[4];
#pragma unroll
    for (int j = 0; j < 4; ++j)
        h[j] = *(const float4*)(hrow + lane * 16 + j * 4);

    float keep = 0.0f;
#pragma unroll
    for (int o = 0; o < 10; ++o) {
        const float* wrow = (o < 2) ? (wc + (size_t)o * HID)
                                    : (wb + (size_t)(o - 2) * HID);
        float acc = 0.0f;
#pragma unroll
        for (int j = 0; j < 4; ++j) {
            const float4 w4 = *(const float4*)(wrow + lane * 16 + j * 4);
            acc += h[j].x * w4.x + h[j].y * w4.y + h[j].z * w4.z + h[j].w * w4.w;
        }
#pragma unroll
        for (int s = 32; s; s >>= 1) acc += __shfl_xor(acc, s, 64);
        if (lane == o) keep = acc;
    }
    if (lane < 2)        out[gw * 2 + lane] = keep + bc[lane];
    else if (lane < 10)  out[NROI * 2 + gw * 8 + (lane - 2)] = keep + bb[lane - 2];
}

// ---------------------------------------------------------------------------
extern "C" void kernel_launch(void* const* d_in, const int* in_sizes, int n_in,
                              void* d_out, int out_size, void* d_ws, size_t ws_size,
                              hipStream_t stream)
{
    const float* x    = (const float*)d_in[0];
    const float* rois = (const float*)d_in[1];
    const float* w1   = (const float*)d_in[2];
    const float* b1   = (const float*)d_in[3];
    const float* w2   = (const float*)d_in[4];
    const float* b2   = (const float*)d_in[5];
    const float* wc   = (const float*)d_in[6];
    const float* bc   = (const float*)d_in[7];
    const float* wb   = (const float*)d_in[8];
    const float* bb   = (const float*)d_in[9];
    float* out = (float*)d_out;

    char* ws = (char*)d_ws;
    const size_t CRB = (size_t)NROI * FANIN * 2;       // 51,380,224
    const size_t W1B = (size_t)HID * FANIN * 2;        // 25,690,112
    const size_t W2B = (size_t)HID * HID * 2;          //  2,097,152
    const size_t PB  = (size_t)NROI * HID * 4;         //  8,388,608 per z-slice
    const size_t HB  = (size_t)NROI * HID * 2;         //  4,194,304
    const size_t XTB = (size_t)4 * IMH * IMW * CCH * 2;// 81,920,000

    const int Z1 = 7;   // FC1 K-split: 12544/7 = 1792 = 28 x 64
    const int Z2 = 4;   // FC2 K-split: 1024/4  = 256 =  4 x 64

    size_t off = 0;
    _Float16* cropsP = (_Float16*)(ws + off); off += CRB;
    _Float16* w1P    = (_Float16*)(ws + off); off += W1B;
    _Float16* w2F    = (_Float16*)(ws + off); off += W2B;
    float*    P      = (float*)(ws + off);    off += (size_t)Z1 * PB;
    _Float16* h1F    = (_Float16*)(ws + off); off += HB;
    _Float16* xT     = (_Float16*)(ws + off); off += XTB;   // total ~224 MB
    float*    h2     = P;   // elementwise alias with P[0] in combine_relu_f32

    // weight prep
    permute_w1_kernel<<<HID, 256, 0, stream>>>(w1, w1P);
    convert_f16<<<1024, 256, 0, stream>>>(w2, w2F, HID * HID / 4);

    // x -> xT (f16, channel-last)
    transpose_f16<<<dim3(2, IMH, 4), 256, 0, stream>>>(x, xT);

    // RoIAlign gather: block per ROI, wave per sample
    roi_gather_kernel<<<NROI, 256, 0, stream>>>(xT, rois, cropsP);

    // FC1: 256x256 dbuf tile, XCD-pinned flat grid (224 blocks)
    gemm_f16_256<<<224, 512, 0, stream>>>(
        cropsP, w1P, P, NROI, HID, FANIN, FANIN / Z1);
    combine_relu_f16<<<(NROI * HID / 4) / 256, 256, 0, stream>>>(P, Z1, b1, h1F);

    // FC2: K = 1024, 128x128 dbuf tile
    gemm_f16<<<dim3(HID / 128, NROI / 128, Z2), 256, 0, stream>>>(
        h1F, w2F, P, NROI, HID, HID, HID / Z2);
    combine_relu_f32<<<(NROI * HID / 4) / 256, 256, 0, stream>>>(P, Z2, b2, h2);

    // heads
    heads_kernel<<<NROI / 4, 256, 0, stream>>>(h2, wc, bc, wb, bb, out);
}

// Round 19
// 196.949 us; speedup vs baseline: 1.3823x; 1.1002x over previous
//
#include <hip/hip_runtime.h>

#define NROI  2048
#define CCH   256
#define IMH   200
#define IMW   200
#define CROP  7
#define PP    49
#define FANIN 12544
#define HID   1024

typedef _Float16 f16x8 __attribute__((ext_vector_type(8)));
typedef _Float16 f16x4 __attribute__((ext_vector_type(4)));
typedef __attribute__((ext_vector_type(4))) float f32x4;

__device__ __forceinline__ void gload16(const void* g, void* l) {
    __builtin_amdgcn_global_load_lds(
        (const __attribute__((address_space(1))) void*)g,
        (__attribute__((address_space(3))) void*)l, 16, 0, 0);
}

// ---------------------------------------------------------------------------
// Fused prep: [0,1600) transpose x->xT; [1600,2624) permute w1; [2624,2688)
// convert w2. One launch; 51.6 KB shared LDS union -> 3 blocks/CU.
// ---------------------------------------------------------------------------
__global__ __launch_bounds__(256) void prep_all(
    const float* __restrict__ x, _Float16* __restrict__ xT,
    const float* __restrict__ w1, _Float16* __restrict__ w1P,
    const float* __restrict__ w2, _Float16* __restrict__ w2F)
{
    __shared__ char smem[51600];
    const int bid = blockIdx.x;
    const int tid = threadIdx.x;

    if (bid < 1600) {
        // ---- transpose+convert: x[b][c][h][w] f32 -> xT[b][h][w][c] f16 ----
        typedef _Float16 Row258[258];
        Row258* t = (Row258*)smem;
        const int b    = bid / 400;
        const int rem  = bid - b * 400;
        const int h    = rem >> 1;
        const int half = rem & 1;
        const int c    = tid;

        const float* src = x + ((size_t)(b * CCH + c) * IMH + h) * IMW + half * 100;
#pragma unroll
        for (int i = 0; i < 25; ++i) {
            const float4 v = *(const float4*)(src + i * 4);
            t[i * 4 + 0][c] = (_Float16)v.x;
            t[i * 4 + 1][c] = (_Float16)v.y;
            t[i * 4 + 2][c] = (_Float16)v.z;
            t[i * 4 + 3][c] = (_Float16)v.w;
        }
        __syncthreads();

        _Float16* dst = xT + ((size_t)(b * IMH + h) * IMW + half * 100) * CCH;
        const int wq = tid >> 5;          // 0..7
        const int l32 = tid & 31;
#pragma unroll
        for (int r = 0; r < 13; ++r) {
            const int w = r * 8 + wq;
            if (w < 100)
                *(f16x8*)(dst + (size_t)w * CCH + l32 * 8) =
                    *(const f16x8*)&t[w][l32 * 8];
        }
    } else if (bid < 2624) {
        // ---- permute w1: w1P[o][p*256+c] = (f16) w1[o][c*49+p] ----
        _Float16* row = (_Float16*)smem;
        const int o = bid - 1600;
        const float* src = w1 + (size_t)o * FANIN;

        for (int g = tid; g < FANIN / 4; g += 256) {
            const float4 v = *(const float4*)(src + g * 4);
            f16x4 f = {(_Float16)v.x, (_Float16)v.y, (_Float16)v.z, (_Float16)v.w};
            *(f16x4*)&row[g * 4] = f;
        }
        __syncthreads();

        _Float16* dst = w1P + (size_t)o * FANIN;
        for (int g = tid; g < FANIN; g += 256) {
            const int p = g >> 8;          // 0..48
            const int c = g & 255;
            dst[g] = row[c * PP + p];
        }
    } else {
        // ---- convert w2 f32 -> f16 ----
        const int cb = bid - 2624;         // 0..63
        for (int g = cb * 256 + tid; g < HID * HID / 4; g += 64 * 256) {
            const float4 v = ((const float4*)w2)[g];
            f16x4 o = {(_Float16)v.x, (_Float16)v.y, (_Float16)v.z, (_Float16)v.w};
            ((f16x4*)w2F)[g] = o;
        }
    }
}

// ---------------------------------------------------------------------------
// RoIAlign gather: block = ROI n, 4 waves; wave = one sample across channels.
// Crops K-order: k' = p*256 + c  (w1 permuted identically).
// ---------------------------------------------------------------------------
__global__ __launch_bounds__(256) void roi_gather_kernel(
    const _Float16* __restrict__ xT, const float* __restrict__ rois,
    _Float16* __restrict__ crops)
{
    const int n    = blockIdx.x;
    const int wave = threadIdx.x >> 6;
    const int lane = threadIdx.x & 63;

    const int   b   = (int)rois[(size_t)n * 5 + 0];
    const float rx1 = rois[(size_t)n * 5 + 1];
    const float ry1 = rois[(size_t)n * 5 + 2];
    const float rx2 = rois[(size_t)n * 5 + 3];
    const float ry2 = rois[(size_t)n * 5 + 4];
    const float bw = (rx2 - rx1) / 7.0f;
    const float bh = (ry2 - ry1) / 7.0f;

    const _Float16* xb = xT + (size_t)b * (IMH * IMW * CCH);
    _Float16* crow = crops + (size_t)n * FANIN;

    for (int p = wave; p < PP; p += 4) {
        const int i = p / 7;           // bin row -> y
        const int j = p - i * 7;       // bin col -> x
        float px = __fadd_rn(rx1, __fmul_rn((float)j + 0.5f, bw));
        float py = __fadd_rn(ry1, __fmul_rn((float)i + 0.5f, bh));
        px = fminf(fmaxf(px, 0.0f), (float)(IMW - 1));
        py = fminf(fmaxf(py, 0.0f), (float)(IMH - 1));
        const float fx = floorf(px), fy = floorf(py);
        const int x0 = (int)fx, y0 = (int)fy;
        const int dxo = (min(x0 + 1, IMW - 1) - x0) * CCH;
        const int dyo = (min(y0 + 1, IMH - 1) - y0) * (IMW * CCH);
        const float wx = px - fx, wy = py - fy;

        const _Float16* cb = xb + (size_t)(y0 * IMW + x0) * CCH + lane * 4;
        const f16x4 A = *(const f16x4*)(cb);
        const f16x4 B = *(const f16x4*)(cb + dxo);
        const f16x4 C = *(const f16x4*)(cb + dyo);
        const f16x4 D = *(const f16x4*)(cb + dyo + dxo);

        f16x4 o;
#pragma unroll
        for (int e = 0; e < 4; ++e) {
            const float v00 = (float)A[e], v01 = (float)B[e];
            const float v10 = (float)C[e], v11 = (float)D[e];
            const float top = v00 + wx * (v01 - v00);
            const float bot = v10 + wx * (v11 - v10);
            o[e] = (_Float16)(top + wy * (bot - top));
        }
        *(f16x4*)(crow + p * CCH + lane * 4) = o;
    }
}

// ---------------------------------------------------------------------------
// FC1 GEMM (NT), 256x256 tile, BK=64, 8 waves, double-buffered 2-phase,
// XCD-pinned flat grid (224 blocks). P partials stored as f16.
// ---------------------------------------------------------------------------
__global__ __launch_bounds__(512, 1) void gemm_f16_256(
    const _Float16* __restrict__ A, const _Float16* __restrict__ B,
    _Float16* __restrict__ P, int M, int N, int K, int kLen)
{
    __shared__ _Float16 lds[2][2][256][64];   // [buf][op][row][slot] 128 KB

    const int flat = blockIdx.x;
    const int xcd  = flat & 7;
    const int idx  = flat >> 3;          // 0..27
    const int bn4  = xcd & 3;            // n-tile 0..3
    const int half = xcd >> 2;           // 0..1
    const int bm8  = half * 4 + (idx & 3);   // m-tile 0..7
    const int z    = idx >> 2;           // 0..6

    const int tid  = threadIdx.x;
    const int wave = tid >> 6;           // 0..7
    const int lane = tid & 63;
    const int bm = bm8 * 256;
    const int bn = bn4 * 256;
    const int kBase = z * kLen;
    const int wr = wave >> 1;            // 0..3 (M)
    const int wc = wave & 1;             // 0..1 (N)

    f32x4 acc[4][8];
#pragma unroll
    for (int i = 0; i < 4; ++i)
#pragma unroll
        for (int j = 0; j < 8; ++j) acc[i][j] = (f32x4){0.f, 0.f, 0.f, 0.f};

    const int r_st = wave * 32 + (lane >> 3);
    const int s_st = ((lane & 7) ^ ((lane >> 4) & 3)) * 8;   // f16 units
    const _Float16* gA = A + (size_t)(bm + r_st) * K + kBase + s_st;
    const _Float16* gB = B + (size_t)(bn + r_st) * K + kBase + s_st;
    const size_t rstep8 = (size_t)8 * K;

    const int li = lane & 15;
    const int hi = lane >> 4;            // 0..3
    const int swb = (li >> 1) & 3;       // row-pair xor term

    // prologue: stage tile 0 into buf 0
    {
        _Float16* dA = &lds[0][0][wave * 32][0];
        _Float16* dB = &lds[0][1][wave * 32][0];
#pragma unroll
        for (int ck = 0; ck < 4; ++ck) {
            gload16(gA + ck * rstep8, dA + ck * 512);
            gload16(gB + ck * rstep8, dB + ck * 512);
        }
    }
    __syncthreads();

    int cur = 0;
    for (int kt = 0; kt < kLen; kt += 64) {
        if (kt + 64 < kLen) {
            _Float16* dA = &lds[cur ^ 1][0][wave * 32][0];
            _Float16* dB = &lds[cur ^ 1][1][wave * 32][0];
#pragma unroll
            for (int ck = 0; ck < 4; ++ck) {
                gload16(gA + kt + 64 + ck * rstep8, dA + ck * 512);
                gload16(gB + kt + 64 + ck * rstep8, dB + ck * 512);
            }
        }

#pragma unroll
        for (int kk = 0; kk < 2; ++kk) {
            const int sw = (((kk << 2) | hi) ^ swb) * 8;     // f16 offset
            f16x8 a[4], b[8];
#pragma unroll
            for (int m = 0; m < 4; ++m)
                a[m] = *(const f16x8*)&lds[cur][0][wr * 64 + m * 16 + li][sw];
#pragma unroll
            for (int n = 0; n < 8; ++n)
                b[n] = *(const f16x8*)&lds[cur][1][wc * 128 + n * 16 + li][sw];
#pragma unroll
            for (int m = 0; m < 4; ++m)
#pragma unroll
                for (int n = 0; n < 8; ++n)
                    acc[m][n] = __builtin_amdgcn_mfma_f32_16x16x32_f16(a[m], b[n], acc[m][n], 0, 0, 0);
        }
        __syncthreads();
        cur ^= 1;
    }

    _Float16* Pz = P + (size_t)z * M * N;
#pragma unroll
    for (int m = 0; m < 4; ++m)
#pragma unroll
        for (int n = 0; n < 8; ++n) {
            const int col = bn + wc * 128 + n * 16 + li;
#pragma unroll
            for (int e = 0; e < 4; ++e) {
                const int row = bm + wr * 64 + m * 16 + hi * 4 + e;
                Pz[(size_t)row * N + col] = (_Float16)acc[m][n][e];
            }
        }
}

// ---------------------------------------------------------------------------
// FC2 GEMM (NT), 128x128 tile, BK=64, double-buffered 2-phase, f16 partials.
// ---------------------------------------------------------------------------
__global__ __launch_bounds__(256, 2) void gemm_f16(
    const _Float16* __restrict__ A, const _Float16* __restrict__ B,
    _Float16* __restrict__ P, int M, int N, int K, int kLen)
{
    __shared__ _Float16 lds[2][2][128][64];   // 64 KB -> 2 blocks/CU

    const int tid  = threadIdx.x;
    const int wave = tid >> 6;
    const int lane = tid & 63;
    const int bm = blockIdx.y * 128;
    const int bn = blockIdx.x * 128;
    const int kBase = blockIdx.z * kLen;
    const int wr = wave >> 1, wc = wave & 1;

    f32x4 acc[4][4];
#pragma unroll
    for (int i = 0; i < 4; ++i)
#pragma unroll
        for (int j = 0; j < 4; ++j) acc[i][j] = (f32x4){0.f, 0.f, 0.f, 0.f};

    const int r_st = wave * 32 + (lane >> 3);
    const int s_st = ((lane & 7) ^ ((lane >> 4) & 3)) * 8;   // f16 units
    const _Float16* gA = A + (size_t)(bm + r_st) * K + kBase + s_st;
    const _Float16* gB = B + (size_t)(bn + r_st) * K + kBase + s_st;
    const size_t rstep8 = (size_t)8 * K;

    const int li = lane & 15;
    const int hi = lane >> 4;            // 0..3
    const int swb = (li >> 1) & 3;       // row-pair xor term

    {
        _Float16* dA = &lds[0][0][wave * 32][0];
        _Float16* dB = &lds[0][1][wave * 32][0];
#pragma unroll
        for (int ck = 0; ck < 4; ++ck) {
            gload16(gA + ck * rstep8, dA + ck * 512);
            gload16(gB + ck * rstep8, dB + ck * 512);
        }
    }
    __syncthreads();

    int cur = 0;
    for (int kt = 0; kt < kLen; kt += 64) {
        if (kt + 64 < kLen) {
            _Float16* dA = &lds[cur ^ 1][0][wave * 32][0];
            _Float16* dB = &lds[cur ^ 1][1][wave * 32][0];
#pragma unroll
            for (int ck = 0; ck < 4; ++ck) {
                gload16(gA + kt + 64 + ck * rstep8, dA + ck * 512);
                gload16(gB + kt + 64 + ck * rstep8, dB + ck * 512);
            }
        }

#pragma unroll
        for (int kk = 0; kk < 2; ++kk) {
            const int sw = (((kk << 2) | hi) ^ swb) * 8;     // f16 offset
            f16x8 a[4], b[4];
#pragma unroll
            for (int m = 0; m < 4; ++m)
                a[m] = *(const f16x8*)&lds[cur][0][wr * 64 + m * 16 + li][sw];
#pragma unroll
            for (int n = 0; n < 4; ++n)
                b[n] = *(const f16x8*)&lds[cur][1][wc * 64 + n * 16 + li][sw];
#pragma unroll
            for (int m = 0; m < 4; ++m)
#pragma unroll
                for (int n = 0; n < 4; ++n)
                    acc[m][n] = __builtin_amdgcn_mfma_f32_16x16x32_f16(a[m], b[n], acc[m][n], 0, 0, 0);
        }
        __syncthreads();
        cur ^= 1;
    }

    _Float16* Pz = P + (size_t)blockIdx.z * M * N;
#pragma unroll
    for (int m = 0; m < 4; ++m)
#pragma unroll
        for (int n = 0; n < 4; ++n) {
            const int col = bn + wc * 64 + n * 16 + li;
#pragma unroll
            for (int e = 0; e < 4; ++e) {
                const int row = bm + wr * 64 + m * 16 + hi * 4 + e;
                Pz[(size_t)row * N + col] = (_Float16)acc[m][n][e];
            }
        }
}

// ---------------------------------------------------------------------------
// relu(sum_z P[z] + bias) -> f16   (P slices are f16; accumulate in f32)
// ---------------------------------------------------------------------------
__global__ __launch_bounds__(256) void combine_relu_f16(
    const _Float16* __restrict__ P, int Z, const float* __restrict__ bias,
    _Float16* __restrict__ H)
{
    const int g = blockIdx.x * 256 + threadIdx.x;      // f16x8 group
    const size_t MN8 = (size_t)NROI * HID / 8;
    float s[8] = {0, 0, 0, 0, 0, 0, 0, 0};
    for (int z = 0; z < Z; ++z) {
        const f16x8 p = ((const f16x8*)P)[z * MN8 + g];
#pragma unroll
        for (int e = 0; e < 8; ++e) s[e] += (float)p[e];
    }
    const int col = (g * 8) & (HID - 1);
    const float4 b0 = *(const float4*)(bias + col);
    const float4 b1 = *(const float4*)(bias + col + 4);
    f16x8 o;
    o[0] = (_Float16)fmaxf(s[0] + b0.x, 0.0f);
    o[1] = (_Float16)fmaxf(s[1] + b0.y, 0.0f);
    o[2] = (_Float16)fmaxf(s[2] + b0.z, 0.0f);
    o[3] = (_Float16)fmaxf(s[3] + b0.w, 0.0f);
    o[4] = (_Float16)fmaxf(s[4] + b1.x, 0.0f);
    o[5] = (_Float16)fmaxf(s[5] + b1.y, 0.0f);
    o[6] = (_Float16)fmaxf(s[6] + b1.z, 0.0f);
    o[7] = (_Float16)fmaxf(s[7] + b1.w, 0.0f);
    ((f16x8*)H)[g] = o;
}

// ---------------------------------------------------------------------------
// relu(sum_z P[z] + bias) -> f32  (H must NOT alias P)
// ---------------------------------------------------------------------------
__global__ __launch_bounds__(256) void combine_relu_f32(
    const _Float16* __restrict__ P, int Z, const float* __restrict__ bias,
    float* __restrict__ H)
{
    const int g = blockIdx.x * 256 + threadIdx.x;      // f16x8 group
    const size_t MN8 = (size_t)NROI * HID / 8;
    float s[8] = {0, 0, 0, 0, 0, 0, 0, 0};
    for (int z = 0; z < Z; ++z) {
        const f16x8 p = ((const f16x8*)P)[z * MN8 + g];
#pragma unroll
        for (int e = 0; e < 8; ++e) s[e] += (float)p[e];
    }
    const int col = (g * 8) & (HID - 1);
    const float4 b0 = *(const float4*)(bias + col);
    const float4 b1 = *(const float4*)(bias + col + 4);
    float4 r0, r1;
    r0.x = fmaxf(s[0] + b0.x, 0.0f);
    r0.y = fmaxf(s[1] + b0.y, 0.0f);
    r0.z = fmaxf(s[2] + b0.z, 0.0f);
    r0.w = fmaxf(s[3] + b0.w, 0.0f);
    r1.x = fmaxf(s[4] + b1.x, 0.0f);
    r1.y = fmaxf(s[5] + b1.y, 0.0f);
    r1.z = fmaxf(s[6] + b1.z, 0.0f);
    r1.w = fmaxf(s[7] + b1.w, 0.0f);
    ((float4*)H)[g * 2]     = r0;
    ((float4*)H)[g * 2 + 1] = r1;
}

// ---------------------------------------------------------------------------
// heads: one wave per ROI row; 10 dots of K=1024, shfl_xor reduce.
// ---------------------------------------------------------------------------
__global__ __launch_bounds__(256) void heads_kernel(
    const float* __restrict__ h2,
    const float* __restrict__ wc, const float* __restrict__ bc,
    const float* __restrict__ wb, const float* __restrict__ bb,
    float* __restrict__ out)
{
    const int gw   = (blockIdx.x * 256 + threadIdx.x) >> 6;
    const int lane = threadIdx.x & 63;
    const float* hrow = h2 + (size_t)gw * HID;

    float4 h[4];
#pragma unroll
    for (int j = 0; j < 4; ++j)
        h[j] = *(const float4*)(hrow + lane * 16 + j * 4);

    float keep = 0.0f;
#pragma unroll
    for (int o = 0; o < 10; ++o) {
        const float* wrow = (o < 2) ? (wc + (size_t)o * HID)
                                    : (wb + (size_t)(o - 2) * HID);
        float acc = 0.0f;
#pragma unroll
        for (int j = 0; j < 4; ++j) {
            const float4 w4 = *(const float4*)(wrow + lane * 16 + j * 4);
            acc += h[j].x * w4.x + h[j].y * w4.y + h[j].z * w4.z + h[j].w * w4.w;
        }
#pragma unroll
        for (int s = 32; s; s >>= 1) acc += __shfl_xor(acc, s, 64);
        if (lane == o) keep = acc;
    }
    if (lane < 2)        out[gw * 2 + lane] = keep + bc[lane];
    else if (lane < 10)  out[NROI * 2 + gw * 8 + (lane - 2)] = keep + bb[lane - 2];
}

// ---------------------------------------------------------------------------
extern "C" void kernel_launch(void* const* d_in, const int* in_sizes, int n_in,
                              void* d_out, int out_size, void* d_ws, size_t ws_size,
                              hipStream_t stream)
{
    const float* x    = (const float*)d_in[0];
    const float* rois = (const float*)d_in[1];
    const float* w1   = (const float*)d_in[2];
    const float* b1   = (const float*)d_in[3];
    const float* w2   = (const float*)d_in[4];
    const float* b2   = (const float*)d_in[5];
    const float* wc   = (const float*)d_in[6];
    const float* bc   = (const float*)d_in[7];
    const float* wb   = (const float*)d_in[8];
    const float* bb   = (const float*)d_in[9];
    float* out = (float*)d_out;

    char* ws = (char*)d_ws;
    const size_t CRB = (size_t)NROI * FANIN * 2;       // 51,380,224
    const size_t W1B = (size_t)HID * FANIN * 2;        // 25,690,112
    const size_t W2B = (size_t)HID * HID * 2;          //  2,097,152
    const size_t PB  = (size_t)NROI * HID * 2;         //  4,194,304 per z (f16)
    const size_t HB  = (size_t)NROI * HID * 2;         //  4,194,304
    const size_t XTB = (size_t)4 * IMH * IMW * CCH * 2;// 81,920,000

    const int Z1 = 7;   // FC1 K-split: 12544/7 = 1792 = 28 x 64
    const int Z2 = 2;   // FC2 K-split: 1024/2  = 512 =  8 x 64

    size_t off = 0;
    _Float16* cropsP = (_Float16*)(ws + off); off += CRB;
    _Float16* w1P    = (_Float16*)(ws + off); off += W1B;
    _Float16* w2F    = (_Float16*)(ws + off); off += W2B;
    _Float16* P      = (_Float16*)(ws + off); off += (size_t)Z1 * PB;
    _Float16* h1F    = (_Float16*)(ws + off); off += HB;
    _Float16* xT     = (_Float16*)(ws + off); off += XTB;   // total ~195 MB
    float*    h2     = (float*)xT;   // xT dead after gather; h2 needs 8.4 MB

    // fused prep: transpose + permute w1 + convert w2 (one launch)
    prep_all<<<2688, 256, 0, stream>>>(x, xT, w1, w1P, w2, w2F);

    // RoIAlign gather: block per ROI, wave per sample
    roi_gather_kernel<<<NROI, 256, 0, stream>>>(xT, rois, cropsP);

    // FC1: 256x256 dbuf tile, XCD-pinned flat grid (224 blocks), f16 partials
    gemm_f16_256<<<224, 512, 0, stream>>>(
        cropsP, w1P, P, NROI, HID, FANIN, FANIN / Z1);
    combine_relu_f16<<<(NROI * HID / 8) / 256, 256, 0, stream>>>(P, Z1, b1, h1F);

    // FC2: K = 1024, 128x128 dbuf tile, Z=2
    gemm_f16<<<dim3(HID / 128, NROI / 128, Z2), 256, 0, stream>>>(
        h1F, w2F, P, NROI, HID, HID, HID / Z2);
    combine_relu_f32<<<(NROI * HID / 8) / 256, 256, 0, stream>>>(P, Z2, b2, h2);

    // heads
    heads_kernel<<<NROI / 4, 256, 0, stream>>>(h2, wc, bc, wb, bb, out);
}